// Round 1
// baseline (6118.337 us; speedup 1.0000x reference)
//
#include <hip/hip_runtime.h>

// ---------------------------------------------------------------------------
// GCNnet: 3x GCNConv (40->40->80->128) + global max pool + MLP(128->512->2) + softmax
// N=100000 nodes, E=1600000 edges, G=512 graphs.
// Round 0: correctness-first. Edge scatter via f32 atomics; self-loops folded
// into the finalize pass (agg + dinv^2 * hW + b, then relu).
// ---------------------------------------------------------------------------

static inline int cdiv(long a, int b) { return (int)((a + b - 1) / b); }
static inline size_t align256(size_t x) { return (x + 255) & ~(size_t)255; }

__global__ void deg_kernel(const int* __restrict__ col, const float* __restrict__ w,
                           float* __restrict__ deg, int E) {
    int e = blockIdx.x * blockDim.x + threadIdx.x;
    if (e < E) atomicAdd(&deg[col[e]], w[e]);
}

// deg -> dinv in place; self-loop contributes +1 so deg+1 > 0 always
__global__ void dinv_kernel(float* __restrict__ deg, int N) {
    int i = blockIdx.x * blockDim.x + threadIdx.x;
    if (i < N) deg[i] = rsqrtf(deg[i] + 1.0f);
}

__global__ void norm_kernel(const int* __restrict__ row, const int* __restrict__ col,
                            const float* __restrict__ w, const float* __restrict__ dinv,
                            float* __restrict__ norm, int E) {
    int e = blockIdx.x * blockDim.x + threadIdx.x;
    if (e < E) norm[e] = dinv[row[e]] * w[e] * dinv[col[e]];
}

// Y[N,FOUT] = X[N,FIN] @ W[FIN,FOUT]  (no bias; bias added in finalize)
template<int FIN, int FOUT>
__global__ void transform_kernel(const float* __restrict__ X, const float* __restrict__ W,
                                 float* __restrict__ Y, int N) {
    __shared__ float ws[FIN * FOUT];
    for (int i = threadIdx.x; i < FIN * FOUT; i += blockDim.x) ws[i] = W[i];
    __syncthreads();
    int idx = blockIdx.x * blockDim.x + threadIdx.x;
    int n = idx / FOUT, j = idx % FOUT;
    if (n >= N) return;
    const float* xr = X + (long)n * FIN;
    float acc = 0.f;
#pragma unroll
    for (int k = 0; k < FIN; ++k) acc += xr[k] * ws[k * FOUT + j];
    Y[idx] = acc;
}

// agg[col[e]] += hW[row[e]] * norm[e]  — float4 per thread, 4 scalar atomics
template<int F>
__global__ void edge_agg_kernel(const int* __restrict__ row, const int* __restrict__ col,
                                const float* __restrict__ norm, const float* __restrict__ hW,
                                float* __restrict__ agg, int E) {
    constexpr int V = F / 4;
    int idx = blockIdx.x * blockDim.x + threadIdx.x;
    int e = idx / V, q = idx % V;
    if (e >= E) return;
    int r = row[e], c = col[e];
    float nm = norm[e];
    const float4 v = *(const float4*)(hW + (long)r * F + q * 4);
    float* dst = agg + (long)c * F + q * 4;
    atomicAdd(dst + 0, v.x * nm);
    atomicAdd(dst + 1, v.y * nm);
    atomicAdd(dst + 2, v.z * nm);
    atomicAdd(dst + 3, v.w * nm);
}

// out = relu(agg + dinv[n]^2 * hW + bias[f])   (self-loop folded in; in-place OK)
template<int F>
__global__ void finalize_kernel(const float* __restrict__ agg, const float* __restrict__ hW,
                                const float* __restrict__ dinv, const float* __restrict__ bias,
                                float* __restrict__ out, int N) {
    int idx = blockIdx.x * blockDim.x + threadIdx.x;
    if (idx >= N * F) return;
    int n = idx / F, f = idx % F;
    float di = dinv[n];
    float v = agg[idx] + di * di * hW[idx] + bias[f];
    out[idx] = fmaxf(v, 0.f);
}

// per-graph feature-wise max; h >= 0 so uint-bit atomicMax is order-correct, init 0
__global__ void pool_kernel(const float* __restrict__ h, const int* __restrict__ batch,
                            unsigned int* __restrict__ g, int N) {
    int idx = blockIdx.x * blockDim.x + threadIdx.x;
    if (idx >= N * 128) return;
    int n = idx >> 7, f = idx & 127;
    float v = h[idx];
    atomicMax(&g[batch[n] * 128 + f], __float_as_uint(v));
}

// one block per graph: relu(g@Wfc1+bfc1) @ Wfc2 + bfc2 -> softmax
__global__ void fc_kernel(const float* __restrict__ g, const float* __restrict__ Wfc1,
                          const float* __restrict__ bfc1, const float* __restrict__ Wfc2,
                          const float* __restrict__ bfc2, float* __restrict__ out) {
    __shared__ float gs[128];
    __shared__ float red0[256], red1[256];
    int b = blockIdx.x, tid = threadIdx.x;
    if (tid < 128) gs[tid] = g[b * 128 + tid];
    __syncthreads();
    float h0 = bfc1[tid], h1 = bfc1[tid + 256];
    for (int k = 0; k < 128; ++k) {
        float gv = gs[k];
        h0 += gv * Wfc1[k * 512 + tid];
        h1 += gv * Wfc1[k * 512 + tid + 256];
    }
    h0 = fmaxf(h0, 0.f); h1 = fmaxf(h1, 0.f);
    red0[tid] = h0 * Wfc2[tid * 2 + 0] + h1 * Wfc2[(tid + 256) * 2 + 0];
    red1[tid] = h0 * Wfc2[tid * 2 + 1] + h1 * Wfc2[(tid + 256) * 2 + 1];
    __syncthreads();
    for (int s = 128; s > 0; s >>= 1) {
        if (tid < s) { red0[tid] += red0[tid + s]; red1[tid] += red1[tid + s]; }
        __syncthreads();
    }
    if (tid == 0) {
        float L0 = red0[0] + bfc2[0], L1 = red1[0] + bfc2[1];
        float m = fmaxf(L0, L1);
        float e0 = expf(L0 - m), e1 = expf(L1 - m);
        float inv = 1.f / (e0 + e1);
        out[b * 2 + 0] = e0 * inv;
        out[b * 2 + 1] = e1 * inv;
    }
}

extern "C" void kernel_launch(void* const* d_in, const int* in_sizes, int n_in,
                              void* d_out, int out_size, void* d_ws, size_t ws_size,
                              hipStream_t stream) {
    const float* x     = (const float*)d_in[0];
    const int*   ei    = (const int*)d_in[1];
    const float* ew    = (const float*)d_in[2];
    const int*   batch = (const int*)d_in[3];
    const float* W1    = (const float*)d_in[4];
    const float* b1    = (const float*)d_in[5];
    const float* W2    = (const float*)d_in[6];
    const float* b2    = (const float*)d_in[7];
    const float* W3    = (const float*)d_in[8];
    const float* b3    = (const float*)d_in[9];
    const float* Wfc1  = (const float*)d_in[10];
    const float* bfc1  = (const float*)d_in[11];
    const float* Wfc2  = (const float*)d_in[12];
    const float* bfc2  = (const float*)d_in[13];

    const int N = in_sizes[3];      // 100000
    const int E = in_sizes[2];      // 1600000
    const int* row = ei;
    const int* col = ei + E;

    char* ws = (char*)d_ws;
    float* dinv = (float*)ws;  ws += align256((size_t)N * 4);
    float* norm = (float*)ws;  ws += align256((size_t)E * 4);
    float* buf0 = (float*)ws;  ws += align256((size_t)N * 128 * 4);   // hW
    float* buf1 = (float*)ws;  ws += align256((size_t)N * 128 * 4);   // agg1 / h2
    float* buf2 = (float*)ws;  ws += align256((size_t)N * 128 * 4);   // h1 / agg3 / h3
    float* g    = (float*)ws;  ws += align256((size_t)512 * 128 * 4);

    const int B = 256;

    // --- gcn_norm ---
    hipMemsetAsync(dinv, 0, (size_t)N * 4, stream);
    deg_kernel<<<cdiv(E, B), B, 0, stream>>>(col, ew, dinv, E);
    dinv_kernel<<<cdiv(N, B), B, 0, stream>>>(dinv, N);
    norm_kernel<<<cdiv(E, B), B, 0, stream>>>(row, col, ew, dinv, norm, E);

    // --- conv1: x[N,40] -> h1[N,40] (buf2) ---
    transform_kernel<40, 40><<<cdiv((long)N * 40, B), B, 0, stream>>>(x, W1, buf0, N);
    hipMemsetAsync(buf1, 0, (size_t)N * 40 * 4, stream);
    edge_agg_kernel<40><<<cdiv((long)E * 10, B), B, 0, stream>>>(row, col, norm, buf0, buf1, E);
    finalize_kernel<40><<<cdiv((long)N * 40, B), B, 0, stream>>>(buf1, buf0, dinv, b1, buf2, N);

    // --- conv2: h1[N,40] -> h2[N,80] (buf1, in-place over agg) ---
    transform_kernel<40, 80><<<cdiv((long)N * 80, B), B, 0, stream>>>(buf2, W2, buf0, N);
    hipMemsetAsync(buf1, 0, (size_t)N * 80 * 4, stream);
    edge_agg_kernel<80><<<cdiv((long)E * 20, B), B, 0, stream>>>(row, col, norm, buf0, buf1, E);
    finalize_kernel<80><<<cdiv((long)N * 80, B), B, 0, stream>>>(buf1, buf0, dinv, b2, buf1, N);

    // --- conv3: h2[N,80] -> h3[N,128] (buf2, in-place over agg) ---
    transform_kernel<80, 128><<<cdiv((long)N * 128, B), B, 0, stream>>>(buf1, W3, buf0, N);
    hipMemsetAsync(buf2, 0, (size_t)N * 128 * 4, stream);
    edge_agg_kernel<128><<<cdiv((long)E * 32, B), B, 0, stream>>>(row, col, norm, buf0, buf2, E);
    finalize_kernel<128><<<cdiv((long)N * 128, B), B, 0, stream>>>(buf2, buf0, dinv, b3, buf2, N);

    // --- global max pool ---
    hipMemsetAsync(g, 0, (size_t)512 * 128 * 4, stream);
    pool_kernel<<<cdiv((long)N * 128, B), B, 0, stream>>>(buf2, batch, (unsigned int*)g, N);

    // --- MLP + softmax ---
    fc_kernel<<<512, 256, 0, stream>>>(g, Wfc1, bfc1, Wfc2, bfc2, (float*)d_out);
}

// Round 2
// 1351.046 us; speedup vs baseline: 4.5286x; 4.5286x over previous
//
#include <hip/hip_runtime.h>

// ---------------------------------------------------------------------------
// GCNnet: 3x GCNConv (40->40->80->128) + global max pool + MLP(128->512->2) + softmax
// N=100000 nodes, E=1600000 edges, G=512 graphs.
// Round 1: scatter-atomics -> destination-CSR + per-node gather reduction.
//   - CSR build: count (int atomics), 1-block LDS scan, fill (cursor atomics,
//     norm fused into the permuted edge values).
//   - gather_kernel: thread = (node, 4 features); register accumulate; single
//     write. Self-loop + bias + relu fused in epilogue. Conv3 fuses the
//     global-max-pool atomicMax directly (h3 never materialized).
// ---------------------------------------------------------------------------

static inline int cdiv(long a, int b) { return (int)((a + b - 1) / b); }
static inline size_t align256(size_t x) { return (x + 255) & ~(size_t)255; }

// per-destination weighted degree + edge count, one pass
__global__ void deg_count_kernel(const int* __restrict__ col, const float* __restrict__ w,
                                 float* __restrict__ deg, int* __restrict__ count, int E) {
    int e = blockIdx.x * blockDim.x + threadIdx.x;
    if (e < E) {
        int c = col[e];
        atomicAdd(&deg[c], w[e]);
        atomicAdd(&count[c], 1);
    }
}

// deg -> dinv in place; self-loop contributes +1 so deg+1 > 0 always
__global__ void dinv_kernel(float* __restrict__ deg, int N) {
    int i = blockIdx.x * blockDim.x + threadIdx.x;
    if (i < N) deg[i] = rsqrtf(deg[i] + 1.0f);
}

// single-block exclusive scan of count[N] -> offs[N+1] (offs[N] = total)
__global__ void scan_kernel(const int* __restrict__ count, int* __restrict__ offs, int N) {
    __shared__ int tmp[1024];
    __shared__ int carry;
    int tid = threadIdx.x;
    if (tid == 0) carry = 0;
    __syncthreads();
    for (int base = 0; base < N; base += 1024) {
        int v = (base + tid < N) ? count[base + tid] : 0;
        tmp[tid] = v;
        __syncthreads();
        for (int off = 1; off < 1024; off <<= 1) {
            int t = (tid >= off) ? tmp[tid - off] : 0;
            __syncthreads();
            tmp[tid] += t;
            __syncthreads();
        }
        if (base + tid < N) offs[base + tid] = carry + tmp[tid] - v;
        __syncthreads();
        if (tid == 0) carry += tmp[1023];
        __syncthreads();
    }
    if (tid == 0) offs[N] = carry;
}

// CSR fill; norm = dinv[row]*w*dinv[col] fused into the permuted edge value
__global__ void fill_kernel(const int* __restrict__ row, const int* __restrict__ col,
                            const float* __restrict__ w, const float* __restrict__ dinv,
                            const int* __restrict__ offs, int* __restrict__ cursor,
                            int* __restrict__ perm_row, float* __restrict__ perm_norm, int E) {
    int e = blockIdx.x * blockDim.x + threadIdx.x;
    if (e >= E) return;
    int r = row[e], c = col[e];
    int pos = offs[c] + atomicAdd(&cursor[c], 1);
    perm_row[pos] = r;
    perm_norm[pos] = dinv[r] * w[e] * dinv[c];
}

// Y[N,FOUT] = X[N,FIN] @ W[FIN,FOUT]  (no bias; handled in gather epilogue)
template<int FIN, int FOUT>
__global__ void transform_kernel(const float* __restrict__ X, const float* __restrict__ W,
                                 float* __restrict__ Y, int N) {
    __shared__ float ws[FIN * FOUT];
    for (int i = threadIdx.x; i < FIN * FOUT; i += blockDim.x) ws[i] = W[i];
    __syncthreads();
    int idx = blockIdx.x * blockDim.x + threadIdx.x;
    int n = idx / FOUT, j = idx % FOUT;
    if (n >= N) return;
    const float* xr = X + (long)n * FIN;
    float acc = 0.f;
#pragma unroll
    for (int k = 0; k < FIN; ++k) acc += xr[k] * ws[k * FOUT + j];
    Y[idx] = acc;
}

// out[d] = relu( sum_{e: col=d} hW[row_e]*norm_e + dinv[d]^2*hW[d] + bias )
// thread = (node, 4 consecutive features). FUSE_POOL: atomicMax into g instead
// of storing (values >= 0 post-relu, g zero-initialized -> uint max is correct).
template<int F, bool FUSE_POOL>
__global__ void gather_kernel(const int* __restrict__ offs, const int* __restrict__ perm_row,
                              const float* __restrict__ perm_norm, const float* __restrict__ hW,
                              const float* __restrict__ dinv, const float* __restrict__ bias,
                              float* __restrict__ out, const int* __restrict__ batch,
                              unsigned int* __restrict__ g, int N) {
    constexpr int TPN = F / 4;
    int idx = blockIdx.x * blockDim.x + threadIdx.x;
    int node = idx / TPN, q = idx % TPN;
    if (node >= N) return;
    int s = offs[node], e = offs[node + 1];
    float ax = 0.f, ay = 0.f, az = 0.f, aw = 0.f;
    for (int j = s; j < e; ++j) {
        int r = perm_row[j];
        float nm = perm_norm[j];
        const float4 v = *(const float4*)(hW + (long)r * F + q * 4);
        ax += v.x * nm; ay += v.y * nm; az += v.z * nm; aw += v.w * nm;
    }
    float di = dinv[node], d2 = di * di;
    const float4 sv = *(const float4*)(hW + (long)node * F + q * 4);
    const float4 bv = *(const float4*)(bias + q * 4);
    ax = fmaxf(ax + d2 * sv.x + bv.x, 0.f);
    ay = fmaxf(ay + d2 * sv.y + bv.y, 0.f);
    az = fmaxf(az + d2 * sv.z + bv.z, 0.f);
    aw = fmaxf(aw + d2 * sv.w + bv.w, 0.f);
    if (FUSE_POOL) {
        unsigned int* gd = g + (long)batch[node] * F + q * 4;
        atomicMax(gd + 0, __float_as_uint(ax));
        atomicMax(gd + 1, __float_as_uint(ay));
        atomicMax(gd + 2, __float_as_uint(az));
        atomicMax(gd + 3, __float_as_uint(aw));
    } else {
        float4 o = make_float4(ax, ay, az, aw);
        *(float4*)(out + (long)node * F + q * 4) = o;
    }
}

// one block per graph: relu(g@Wfc1+bfc1) @ Wfc2 + bfc2 -> softmax
__global__ void fc_kernel(const float* __restrict__ g, const float* __restrict__ Wfc1,
                          const float* __restrict__ bfc1, const float* __restrict__ Wfc2,
                          const float* __restrict__ bfc2, float* __restrict__ out) {
    __shared__ float gs[128];
    __shared__ float red0[256], red1[256];
    int b = blockIdx.x, tid = threadIdx.x;
    if (tid < 128) gs[tid] = g[b * 128 + tid];
    __syncthreads();
    float h0 = bfc1[tid], h1 = bfc1[tid + 256];
    for (int k = 0; k < 128; ++k) {
        float gv = gs[k];
        h0 += gv * Wfc1[k * 512 + tid];
        h1 += gv * Wfc1[k * 512 + tid + 256];
    }
    h0 = fmaxf(h0, 0.f); h1 = fmaxf(h1, 0.f);
    red0[tid] = h0 * Wfc2[tid * 2 + 0] + h1 * Wfc2[(tid + 256) * 2 + 0];
    red1[tid] = h0 * Wfc2[tid * 2 + 1] + h1 * Wfc2[(tid + 256) * 2 + 1];
    __syncthreads();
    for (int s = 128; s > 0; s >>= 1) {
        if (tid < s) { red0[tid] += red0[tid + s]; red1[tid] += red1[tid + s]; }
        __syncthreads();
    }
    if (tid == 0) {
        float L0 = red0[0] + bfc2[0], L1 = red1[0] + bfc2[1];
        float m = fmaxf(L0, L1);
        float e0 = expf(L0 - m), e1 = expf(L1 - m);
        float inv = 1.f / (e0 + e1);
        out[b * 2 + 0] = e0 * inv;
        out[b * 2 + 1] = e1 * inv;
    }
}

extern "C" void kernel_launch(void* const* d_in, const int* in_sizes, int n_in,
                              void* d_out, int out_size, void* d_ws, size_t ws_size,
                              hipStream_t stream) {
    const float* x     = (const float*)d_in[0];
    const int*   ei    = (const int*)d_in[1];
    const float* ew    = (const float*)d_in[2];
    const int*   batch = (const int*)d_in[3];
    const float* W1    = (const float*)d_in[4];
    const float* b1    = (const float*)d_in[5];
    const float* W2    = (const float*)d_in[6];
    const float* b2    = (const float*)d_in[7];
    const float* W3    = (const float*)d_in[8];
    const float* b3    = (const float*)d_in[9];
    const float* Wfc1  = (const float*)d_in[10];
    const float* bfc1  = (const float*)d_in[11];
    const float* Wfc2  = (const float*)d_in[12];
    const float* bfc2  = (const float*)d_in[13];

    const int N = in_sizes[3];      // 100000
    const int E = in_sizes[2];      // 1600000
    const int* row = ei;
    const int* col = ei + E;

    char* ws = (char*)d_ws;
    float* dinv      = (float*)ws; ws += align256((size_t)N * 4);
    int*   count     = (int*)ws;   ws += align256((size_t)N * 4);
    int*   offs      = (int*)ws;   ws += align256((size_t)(N + 1) * 4);
    int*   cursor    = (int*)ws;   ws += align256((size_t)N * 4);
    int*   perm_row  = (int*)ws;   ws += align256((size_t)E * 4);
    float* perm_norm = (float*)ws; ws += align256((size_t)E * 4);
    float* A         = (float*)ws; ws += align256((size_t)N * 128 * 4);  // hW
    float* Bf        = (float*)ws; ws += align256((size_t)N * 128 * 4);  // h
    float* g         = (float*)ws; ws += align256((size_t)512 * 128 * 4);

    const int B = 256;

    // --- gcn_norm + CSR build ---
    hipMemsetAsync(dinv, 0, (size_t)N * 4, stream);
    hipMemsetAsync(count, 0, (size_t)N * 4, stream);
    hipMemsetAsync(cursor, 0, (size_t)N * 4, stream);
    deg_count_kernel<<<cdiv(E, B), B, 0, stream>>>(col, ew, dinv, count, E);
    dinv_kernel<<<cdiv(N, B), B, 0, stream>>>(dinv, N);
    scan_kernel<<<1, 1024, 0, stream>>>(count, offs, N);
    fill_kernel<<<cdiv(E, B), B, 0, stream>>>(row, col, ew, dinv, offs, cursor,
                                              perm_row, perm_norm, E);

    // --- conv1: x[N,40] -> h1[N,40] (Bf) ---
    transform_kernel<40, 40><<<cdiv((long)N * 40, B), B, 0, stream>>>(x, W1, A, N);
    gather_kernel<40, false><<<cdiv((long)N * 10, B), B, 0, stream>>>(
        offs, perm_row, perm_norm, A, dinv, b1, Bf, nullptr, nullptr, N);

    // --- conv2: h1[N,40] -> h2[N,80] (Bf) ---
    transform_kernel<40, 80><<<cdiv((long)N * 80, B), B, 0, stream>>>(Bf, W2, A, N);
    gather_kernel<80, false><<<cdiv((long)N * 20, B), B, 0, stream>>>(
        offs, perm_row, perm_norm, A, dinv, b2, Bf, nullptr, nullptr, N);

    // --- conv3: h2[N,80] -> pooled g directly (h3 never materialized) ---
    transform_kernel<80, 128><<<cdiv((long)N * 128, B), B, 0, stream>>>(Bf, W3, A, N);
    hipMemsetAsync(g, 0, (size_t)512 * 128 * 4, stream);
    gather_kernel<128, true><<<cdiv((long)N * 32, B), B, 0, stream>>>(
        offs, perm_row, perm_norm, A, dinv, b3, nullptr, batch, (unsigned int*)g, N);

    // --- MLP + softmax ---
    fc_kernel<<<512, 256, 0, stream>>>(g, Wfc1, bfc1, Wfc2, bfc2, (float*)d_out);
}

// Round 3
// 1032.480 us; speedup vs baseline: 5.9259x; 1.3085x over previous
//
#include <hip/hip_runtime.h>

// ---------------------------------------------------------------------------
// GCNnet: 3x GCNConv (40->40->80->128) + global max pool + MLP(128->512->2) + softmax
// N=100000 nodes, E=1600000 edges, G=512 graphs.
// Round 2:
//  - Aggregate-first: (A*H)*W instead of A*(H*W). Gathers run at widths
//    40/40/80 instead of 40/80/128; bias+relu fused into GEMM epilogue.
//  - transform -> register-blocked GEMM: thread = (2 nodes x 4 feats),
//    W in LDS (ds_read_b128), X rows as broadcast float4 L1 hits.
//    Per K-step: 1 LDS b128 + 8 FMA -> VALU-bound (~15us for 80x128).
//  - conv3 GEMM fuses global-max-pool atomicMax (h3 never materialized).
// ---------------------------------------------------------------------------

static inline int cdiv(long a, int b) { return (int)((a + b - 1) / b); }
static inline size_t align256(size_t x) { return (x + 255) & ~(size_t)255; }

// per-destination weighted degree + edge count, one pass
__global__ void deg_count_kernel(const int* __restrict__ col, const float* __restrict__ w,
                                 float* __restrict__ deg, int* __restrict__ count, int E) {
    int e = blockIdx.x * blockDim.x + threadIdx.x;
    if (e < E) {
        int c = col[e];
        atomicAdd(&deg[c], w[e]);
        atomicAdd(&count[c], 1);
    }
}

// deg -> dinv in place; self-loop contributes +1 so deg+1 > 0 always
__global__ void dinv_kernel(float* __restrict__ deg, int N) {
    int i = blockIdx.x * blockDim.x + threadIdx.x;
    if (i < N) deg[i] = rsqrtf(deg[i] + 1.0f);
}

// single-block exclusive scan of count[N] -> offs[N+1] (offs[N] = total)
__global__ void scan_kernel(const int* __restrict__ count, int* __restrict__ offs, int N) {
    __shared__ int tmp[1024];
    __shared__ int carry;
    int tid = threadIdx.x;
    if (tid == 0) carry = 0;
    __syncthreads();
    for (int base = 0; base < N; base += 1024) {
        int v = (base + tid < N) ? count[base + tid] : 0;
        tmp[tid] = v;
        __syncthreads();
        for (int off = 1; off < 1024; off <<= 1) {
            int t = (tid >= off) ? tmp[tid - off] : 0;
            __syncthreads();
            tmp[tid] += t;
            __syncthreads();
        }
        if (base + tid < N) offs[base + tid] = carry + tmp[tid] - v;
        __syncthreads();
        if (tid == 0) carry += tmp[1023];
        __syncthreads();
    }
    if (tid == 0) offs[N] = carry;
}

// CSR fill; norm = dinv[row]*w*dinv[col] fused into the permuted edge value
__global__ void fill_kernel(const int* __restrict__ row, const int* __restrict__ col,
                            const float* __restrict__ w, const float* __restrict__ dinv,
                            const int* __restrict__ offs, int* __restrict__ cursor,
                            int* __restrict__ perm_row, float* __restrict__ perm_norm, int E) {
    int e = blockIdx.x * blockDim.x + threadIdx.x;
    if (e >= E) return;
    int r = row[e], c = col[e];
    int pos = offs[c] + atomicAdd(&cursor[c], 1);
    perm_row[pos] = r;
    perm_norm[pos] = dinv[r] * w[e] * dinv[c];
}

// agg[d] = sum_{e: col=d} H[row_e]*norm_e + dinv[d]^2*H[d]   (pure aggregation)
// thread = (node, 4 consecutive features)
template<int F>
__global__ void gather_kernel(const int* __restrict__ offs, const int* __restrict__ perm_row,
                              const float* __restrict__ perm_norm, const float* __restrict__ H,
                              const float* __restrict__ dinv, float* __restrict__ agg, int N) {
    constexpr int TPN = F / 4;
    int idx = blockIdx.x * blockDim.x + threadIdx.x;
    int node = idx / TPN, q = idx % TPN;
    if (node >= N) return;
    int s = offs[node], e = offs[node + 1];
    float ax = 0.f, ay = 0.f, az = 0.f, aw = 0.f;
    for (int j = s; j < e; ++j) {
        int r = perm_row[j];
        float nm = perm_norm[j];
        const float4 v = *(const float4*)(H + (long)r * F + q * 4);
        ax += v.x * nm; ay += v.y * nm; az += v.z * nm; aw += v.w * nm;
    }
    float di = dinv[node], d2 = di * di;
    const float4 sv = *(const float4*)(H + (long)node * F + q * 4);
    float4 o = make_float4(ax + d2 * sv.x, ay + d2 * sv.y, az + d2 * sv.z, aw + d2 * sv.w);
    *(float4*)(agg + (long)node * F + q * 4) = o;
}

// out[N,FOUT] = relu(X[N,K] @ W[K,FOUT] + bias)
// thread = (2 nodes, 4 features); W staged in LDS; per K-step 1 ds_read_b128 + 8 FMA.
// FUSE_POOL: atomicMax into g (uint bits; values >= 0 post-relu, g zero-init).
template<int K, int FOUT, bool FUSE_POOL>
__global__ __launch_bounds__(256)
void gemm_kernel(const float* __restrict__ X, const float* __restrict__ W,
                 const float* __restrict__ bias, float* __restrict__ out,
                 const int* __restrict__ batch, unsigned int* __restrict__ g, int N) {
    constexpr int TPP = FOUT / 4;   // threads per node-pair
    __shared__ float ws[K * FOUT];
    for (int i = threadIdx.x; i < K * FOUT; i += 256) ws[i] = W[i];
    __syncthreads();
    int idx = blockIdx.x * 256 + threadIdx.x;
    int p = idx / TPP, q = idx % TPP;
    int n0 = p * 2;
    if (n0 >= N) return;
    bool has1 = (n0 + 1) < N;
    const float4* xr0 = (const float4*)(X + (long)n0 * K);
    const float4* xr1 = has1 ? (const float4*)(X + (long)(n0 + 1) * K) : xr0;
    const float* wq = ws + q * 4;
    float4 a0 = make_float4(0.f, 0.f, 0.f, 0.f);
    float4 a1 = make_float4(0.f, 0.f, 0.f, 0.f);
#pragma unroll
    for (int i = 0; i < K / 4; ++i) {
        float4 x0 = xr0[i];
        float4 x1 = xr1[i];
        const float* xx0 = (const float*)&x0;
        const float* xx1 = (const float*)&x1;
#pragma unroll
        for (int j = 0; j < 4; ++j) {
            float4 wv = *(const float4*)(wq + (i * 4 + j) * FOUT);
            float v0 = xx0[j], v1 = xx1[j];
            a0.x += v0 * wv.x; a0.y += v0 * wv.y; a0.z += v0 * wv.z; a0.w += v0 * wv.w;
            a1.x += v1 * wv.x; a1.y += v1 * wv.y; a1.z += v1 * wv.z; a1.w += v1 * wv.w;
        }
    }
    float4 bv = *(const float4*)(bias + q * 4);
    a0.x = fmaxf(a0.x + bv.x, 0.f); a0.y = fmaxf(a0.y + bv.y, 0.f);
    a0.z = fmaxf(a0.z + bv.z, 0.f); a0.w = fmaxf(a0.w + bv.w, 0.f);
    a1.x = fmaxf(a1.x + bv.x, 0.f); a1.y = fmaxf(a1.y + bv.y, 0.f);
    a1.z = fmaxf(a1.z + bv.z, 0.f); a1.w = fmaxf(a1.w + bv.w, 0.f);
    if (FUSE_POOL) {
        unsigned int* g0 = g + (long)batch[n0] * FOUT + q * 4;
        atomicMax(g0 + 0, __float_as_uint(a0.x));
        atomicMax(g0 + 1, __float_as_uint(a0.y));
        atomicMax(g0 + 2, __float_as_uint(a0.z));
        atomicMax(g0 + 3, __float_as_uint(a0.w));
        if (has1) {
            unsigned int* g1 = g + (long)batch[n0 + 1] * FOUT + q * 4;
            atomicMax(g1 + 0, __float_as_uint(a1.x));
            atomicMax(g1 + 1, __float_as_uint(a1.y));
            atomicMax(g1 + 2, __float_as_uint(a1.z));
            atomicMax(g1 + 3, __float_as_uint(a1.w));
        }
    } else {
        *(float4*)(out + (long)n0 * FOUT + q * 4) = a0;
        if (has1) *(float4*)(out + (long)(n0 + 1) * FOUT + q * 4) = a1;
    }
}

// one block per graph: relu(g@Wfc1+bfc1) @ Wfc2 + bfc2 -> softmax
__global__ void fc_kernel(const float* __restrict__ g, const float* __restrict__ Wfc1,
                          const float* __restrict__ bfc1, const float* __restrict__ Wfc2,
                          const float* __restrict__ bfc2, float* __restrict__ out) {
    __shared__ float gs[128];
    __shared__ float red0[256], red1[256];
    int b = blockIdx.x, tid = threadIdx.x;
    if (tid < 128) gs[tid] = g[b * 128 + tid];
    __syncthreads();
    float h0 = bfc1[tid], h1 = bfc1[tid + 256];
    for (int k = 0; k < 128; ++k) {
        float gv = gs[k];
        h0 += gv * Wfc1[k * 512 + tid];
        h1 += gv * Wfc1[k * 512 + tid + 256];
    }
    h0 = fmaxf(h0, 0.f); h1 = fmaxf(h1, 0.f);
    red0[tid] = h0 * Wfc2[tid * 2 + 0] + h1 * Wfc2[(tid + 256) * 2 + 0];
    red1[tid] = h0 * Wfc2[tid * 2 + 1] + h1 * Wfc2[(tid + 256) * 2 + 1];
    __syncthreads();
    for (int s = 128; s > 0; s >>= 1) {
        if (tid < s) { red0[tid] += red0[tid + s]; red1[tid] += red1[tid + s]; }
        __syncthreads();
    }
    if (tid == 0) {
        float L0 = red0[0] + bfc2[0], L1 = red1[0] + bfc2[1];
        float m = fmaxf(L0, L1);
        float e0 = expf(L0 - m), e1 = expf(L1 - m);
        float inv = 1.f / (e0 + e1);
        out[b * 2 + 0] = e0 * inv;
        out[b * 2 + 1] = e1 * inv;
    }
}

extern "C" void kernel_launch(void* const* d_in, const int* in_sizes, int n_in,
                              void* d_out, int out_size, void* d_ws, size_t ws_size,
                              hipStream_t stream) {
    const float* x     = (const float*)d_in[0];
    const int*   ei    = (const int*)d_in[1];
    const float* ew    = (const float*)d_in[2];
    const int*   batch = (const int*)d_in[3];
    const float* W1    = (const float*)d_in[4];
    const float* b1    = (const float*)d_in[5];
    const float* W2    = (const float*)d_in[6];
    const float* b2    = (const float*)d_in[7];
    const float* W3    = (const float*)d_in[8];
    const float* b3    = (const float*)d_in[9];
    const float* Wfc1  = (const float*)d_in[10];
    const float* bfc1  = (const float*)d_in[11];
    const float* Wfc2  = (const float*)d_in[12];
    const float* bfc2  = (const float*)d_in[13];

    const int N = in_sizes[3];      // 100000
    const int E = in_sizes[2];      // 1600000
    const int* row = ei;
    const int* col = ei + E;

    char* ws = (char*)d_ws;
    float* dinv      = (float*)ws; ws += align256((size_t)N * 4);
    int*   count     = (int*)ws;   ws += align256((size_t)N * 4);
    int*   offs      = (int*)ws;   ws += align256((size_t)(N + 1) * 4);
    int*   cursor    = (int*)ws;   ws += align256((size_t)N * 4);
    int*   perm_row  = (int*)ws;   ws += align256((size_t)E * 4);
    float* perm_norm = (float*)ws; ws += align256((size_t)E * 4);
    float* bufA      = (float*)ws; ws += align256((size_t)N * 128 * 4);  // agg
    float* bufB      = (float*)ws; ws += align256((size_t)N * 128 * 4);  // H (prev layer)
    float* g         = (float*)ws; ws += align256((size_t)512 * 128 * 4);

    const int B = 256;

    // --- gcn_norm + CSR build ---
    hipMemsetAsync(dinv, 0, (size_t)N * 4, stream);
    hipMemsetAsync(count, 0, (size_t)N * 4, stream);
    hipMemsetAsync(cursor, 0, (size_t)N * 4, stream);
    deg_count_kernel<<<cdiv(E, B), B, 0, stream>>>(col, ew, dinv, count, E);
    dinv_kernel<<<cdiv(N, B), B, 0, stream>>>(dinv, N);
    scan_kernel<<<1, 1024, 0, stream>>>(count, offs, N);
    fill_kernel<<<cdiv(E, B), B, 0, stream>>>(row, col, ew, dinv, offs, cursor,
                                              perm_row, perm_norm, E);

    const long npair_thr = ((long)(N + 1) / 2);

    // --- conv1: agg = A*x (40-wide), H1 = relu(agg@W1 + b1) -> bufB ---
    gather_kernel<40><<<cdiv((long)N * 10, B), B, 0, stream>>>(
        offs, perm_row, perm_norm, x, dinv, bufA, N);
    gemm_kernel<40, 40, false><<<cdiv(npair_thr * 10, B), B, 0, stream>>>(
        bufA, W1, b1, bufB, nullptr, nullptr, N);

    // --- conv2: agg = A*H1 (40-wide), H2 = relu(agg@W2 + b2) -> bufB ---
    gather_kernel<40><<<cdiv((long)N * 10, B), B, 0, stream>>>(
        offs, perm_row, perm_norm, bufB, dinv, bufA, N);
    gemm_kernel<40, 80, false><<<cdiv(npair_thr * 20, B), B, 0, stream>>>(
        bufA, W2, b2, bufB, nullptr, nullptr, N);

    // --- conv3: agg = A*H2 (80-wide), pool(relu(agg@W3 + b3)) -> g directly ---
    gather_kernel<80><<<cdiv((long)N * 20, B), B, 0, stream>>>(
        offs, perm_row, perm_norm, bufB, dinv, bufA, N);
    hipMemsetAsync(g, 0, (size_t)512 * 128 * 4, stream);
    gemm_kernel<80, 128, true><<<cdiv(npair_thr * 32, B), B, 0, stream>>>(
        bufA, W3, b3, nullptr, batch, (unsigned int*)g, N);

    // --- MLP + softmax ---
    fc_kernel<<<512, 256, 0, stream>>>(g, Wfc1, bfc1, Wfc2, bfc2, (float*)d_out);
}

// Round 4
// 706.125 us; speedup vs baseline: 8.6647x; 1.4622x over previous
//
#include <hip/hip_runtime.h>

// ---------------------------------------------------------------------------
// GCNnet: 3x GCNConv (40->40->80->128) + global max pool + MLP(128->512->2) + softmax
// N=100000 nodes, E=1600000 edges, G=512 graphs.
// Round 3:
//  - conv3 GEMM pool fusion now hierarchical: 2-graph LDS max window per block
//    (batch sorted, 16 consecutive nodes/block), zero-skipping flush ->
//    ~0.8M global atomics instead of 12.8M (WRITE_SIZE 200MB -> ~15MB).
//  - gather: 4-edge unroll, 4 independent load chains (was 1 -> latency-bound).
//  - scan 4-wide; fill reuses count via atomicSub (cursor array dropped).
//  - GEMM K-loop unroll capped at 4 (VGPR 172 -> ~100, occupancy up).
// ---------------------------------------------------------------------------

static inline int cdiv(long a, int b) { return (int)((a + b - 1) / b); }
static inline size_t align256(size_t x) { return (x + 255) & ~(size_t)255; }

// per-destination weighted degree + edge count, one pass
__global__ void deg_count_kernel(const int* __restrict__ col, const float* __restrict__ w,
                                 float* __restrict__ deg, int* __restrict__ count, int E) {
    int e = blockIdx.x * blockDim.x + threadIdx.x;
    if (e < E) {
        int c = col[e];
        atomicAdd(&deg[c], w[e]);
        atomicAdd(&count[c], 1);
    }
}

// deg -> dinv in place; self-loop contributes +1 so deg+1 > 0 always
__global__ void dinv_kernel(float* __restrict__ deg, int N) {
    int i = blockIdx.x * blockDim.x + threadIdx.x;
    if (i < N) deg[i] = rsqrtf(deg[i] + 1.0f);
}

// single-block exclusive scan of count[N] -> offs[N+1], 4 elements/thread
__global__ void scan_kernel(const int* __restrict__ count, int* __restrict__ offs, int N) {
    __shared__ int tmp[1024];
    __shared__ int carry;
    int tid = threadIdx.x;
    if (tid == 0) carry = 0;
    __syncthreads();
    for (int base = 0; base < N; base += 4096) {
        int i0 = base + tid * 4;
        int v0 = (i0 + 0 < N) ? count[i0 + 0] : 0;
        int v1 = (i0 + 1 < N) ? count[i0 + 1] : 0;
        int v2 = (i0 + 2 < N) ? count[i0 + 2] : 0;
        int v3 = (i0 + 3 < N) ? count[i0 + 3] : 0;
        int sum = v0 + v1 + v2 + v3;
        tmp[tid] = sum;
        __syncthreads();
        for (int off = 1; off < 1024; off <<= 1) {
            int t = (tid >= off) ? tmp[tid - off] : 0;
            __syncthreads();
            tmp[tid] += t;
            __syncthreads();
        }
        int pre = carry + tmp[tid] - sum;
        if (i0 + 0 < N) offs[i0 + 0] = pre;
        if (i0 + 1 < N) offs[i0 + 1] = pre + v0;
        if (i0 + 2 < N) offs[i0 + 2] = pre + v0 + v1;
        if (i0 + 3 < N) offs[i0 + 3] = pre + v0 + v1 + v2;
        __syncthreads();
        if (tid == 0) carry += tmp[1023];
        __syncthreads();
    }
    if (tid == 0) offs[N] = carry;
}

// CSR fill; norm fused; consumes count via atomicSub (segment order reversed — irrelevant)
__global__ void fill_kernel(const int* __restrict__ row, const int* __restrict__ col,
                            const float* __restrict__ w, const float* __restrict__ dinv,
                            const int* __restrict__ offs, int* __restrict__ count,
                            int* __restrict__ perm_row, float* __restrict__ perm_norm, int E) {
    int e = blockIdx.x * blockDim.x + threadIdx.x;
    if (e >= E) return;
    int r = row[e], c = col[e];
    int pos = offs[c] + atomicSub(&count[c], 1) - 1;
    perm_row[pos] = r;
    perm_norm[pos] = dinv[r] * w[e] * dinv[c];
}

// agg[d] = sum_{e: col=d} H[row_e]*norm_e + dinv[d]^2*H[d]
// thread = (node, 4 feats); 4-edge unroll -> 4 independent load chains
template<int F>
__global__ void gather_kernel(const int* __restrict__ offs, const int* __restrict__ perm_row,
                              const float* __restrict__ perm_norm, const float* __restrict__ H,
                              const float* __restrict__ dinv, float* __restrict__ agg, int N) {
    constexpr int TPN = F / 4;
    int idx = blockIdx.x * blockDim.x + threadIdx.x;
    int node = idx / TPN, q = idx % TPN;
    if (node >= N) return;
    int s = offs[node], e = offs[node + 1];
    float4 a0 = make_float4(0.f, 0.f, 0.f, 0.f);
    float4 a1 = make_float4(0.f, 0.f, 0.f, 0.f);
    int j = s;
    for (; j + 4 <= e; j += 4) {
        int r0 = perm_row[j + 0], r1 = perm_row[j + 1];
        int r2 = perm_row[j + 2], r3 = perm_row[j + 3];
        float m0 = perm_norm[j + 0], m1 = perm_norm[j + 1];
        float m2 = perm_norm[j + 2], m3 = perm_norm[j + 3];
        float4 v0 = *(const float4*)(H + (long)r0 * F + q * 4);
        float4 v1 = *(const float4*)(H + (long)r1 * F + q * 4);
        float4 v2 = *(const float4*)(H + (long)r2 * F + q * 4);
        float4 v3 = *(const float4*)(H + (long)r3 * F + q * 4);
        a0.x += v0.x * m0; a0.y += v0.y * m0; a0.z += v0.z * m0; a0.w += v0.w * m0;
        a1.x += v1.x * m1; a1.y += v1.y * m1; a1.z += v1.z * m1; a1.w += v1.w * m1;
        a0.x += v2.x * m2; a0.y += v2.y * m2; a0.z += v2.z * m2; a0.w += v2.w * m2;
        a1.x += v3.x * m3; a1.y += v3.y * m3; a1.z += v3.z * m3; a1.w += v3.w * m3;
    }
    for (; j < e; ++j) {
        int r = perm_row[j];
        float nm = perm_norm[j];
        float4 v = *(const float4*)(H + (long)r * F + q * 4);
        a0.x += v.x * nm; a0.y += v.y * nm; a0.z += v.z * nm; a0.w += v.w * nm;
    }
    float di = dinv[node], d2 = di * di;
    const float4 sv = *(const float4*)(H + (long)node * F + q * 4);
    float4 o = make_float4(a0.x + a1.x + d2 * sv.x, a0.y + a1.y + d2 * sv.y,
                           a0.z + a1.z + d2 * sv.z, a0.w + a1.w + d2 * sv.w);
    *(float4*)(agg + (long)node * F + q * 4) = o;
}

// out[N,FOUT] = relu(X[N,K] @ W[K,FOUT] + bias); thread = (2 nodes, 4 feats), W in LDS.
// FUSE_POOL: hierarchical max-pool — 2-graph LDS window (batch sorted), then
// zero-skipping global atomicMax flush; fallback direct atomics if rel >= 2.
template<int K, int FOUT, bool FUSE_POOL>
__global__ __launch_bounds__(256)
void gemm_kernel(const float* __restrict__ X, const float* __restrict__ W,
                 const float* __restrict__ bias, float* __restrict__ out,
                 const int* __restrict__ batch, unsigned int* __restrict__ g, int N) {
    constexpr int TPP = FOUT / 4;          // threads per node-pair
    constexpr int NPB = 2 * (256 / TPP);   // nodes per block
    __shared__ float ws[K * FOUT];
    __shared__ unsigned int gma[FUSE_POOL ? 2 * FOUT : 1];
    __shared__ int gfirst;
    for (int i = threadIdx.x; i < K * FOUT; i += 256) ws[i] = W[i];
    if (FUSE_POOL) {
        if (threadIdx.x == 0) gfirst = batch[min((int)(blockIdx.x * NPB), N - 1)];
        for (int i = threadIdx.x; i < 2 * FOUT; i += 256) gma[i] = 0u;
    }
    __syncthreads();

    int idx = blockIdx.x * 256 + threadIdx.x;
    int p = idx / TPP, q = idx % TPP;
    int n0 = p * 2;
    bool valid = n0 < N;
    bool has1 = (n0 + 1) < N;
    if (!FUSE_POOL && !valid) return;   // no later barriers on this path
    int cn0 = valid ? n0 : 0;
    int cn1 = has1 ? (n0 + 1) : cn0;
    const float4* xr0 = (const float4*)(X + (long)cn0 * K);
    const float4* xr1 = (const float4*)(X + (long)cn1 * K);
    const float* wq = ws + q * 4;
    float4 a0 = make_float4(0.f, 0.f, 0.f, 0.f);
    float4 a1 = make_float4(0.f, 0.f, 0.f, 0.f);
#pragma unroll 4
    for (int i = 0; i < K / 4; ++i) {
        float4 x0 = xr0[i];
        float4 x1 = xr1[i];
        const float* xx0 = (const float*)&x0;
        const float* xx1 = (const float*)&x1;
#pragma unroll
        for (int j = 0; j < 4; ++j) {
            float4 wv = *(const float4*)(wq + (i * 4 + j) * FOUT);
            float v0 = xx0[j], v1 = xx1[j];
            a0.x += v0 * wv.x; a0.y += v0 * wv.y; a0.z += v0 * wv.z; a0.w += v0 * wv.w;
            a1.x += v1 * wv.x; a1.y += v1 * wv.y; a1.z += v1 * wv.z; a1.w += v1 * wv.w;
        }
    }
    float4 bv = *(const float4*)(bias + q * 4);
    a0.x = fmaxf(a0.x + bv.x, 0.f); a0.y = fmaxf(a0.y + bv.y, 0.f);
    a0.z = fmaxf(a0.z + bv.z, 0.f); a0.w = fmaxf(a0.w + bv.w, 0.f);
    a1.x = fmaxf(a1.x + bv.x, 0.f); a1.y = fmaxf(a1.y + bv.y, 0.f);
    a1.z = fmaxf(a1.z + bv.z, 0.f); a1.w = fmaxf(a1.w + bv.w, 0.f);

    if (!FUSE_POOL) {
        *(float4*)(out + (long)n0 * FOUT + q * 4) = a0;
        if (has1) *(float4*)(out + (long)(n0 + 1) * FOUT + q * 4) = a1;
        return;
    }

    // ---- hierarchical pool ----
    auto push4 = [&](const float4& a, int node) {
        unsigned int bx = __float_as_uint(a.x), by = __float_as_uint(a.y);
        unsigned int bz = __float_as_uint(a.z), bw = __float_as_uint(a.w);
        int rel = batch[node] - gfirst;
        if (rel < 2) {
            unsigned int* d = gma + rel * FOUT + q * 4;
            atomicMax(d + 0, bx); atomicMax(d + 1, by);
            atomicMax(d + 2, bz); atomicMax(d + 3, bw);
        } else {
            unsigned int* d = g + (long)batch[node] * FOUT + q * 4;
            atomicMax(d + 0, bx); atomicMax(d + 1, by);
            atomicMax(d + 2, bz); atomicMax(d + 3, bw);
        }
    };
    if (valid) {
        push4(a0, n0);
        if (has1) push4(a1, n0 + 1);
    }
    __syncthreads();
    for (int i = threadIdx.x; i < 2 * FOUT; i += 256) {
        unsigned int v = gma[i];
        if (v) atomicMax(&g[(long)(gfirst + i / FOUT) * FOUT + (i % FOUT)], v);
    }
}

// one block per graph: relu(g@Wfc1+bfc1) @ Wfc2 + bfc2 -> softmax
__global__ void fc_kernel(const float* __restrict__ g, const float* __restrict__ Wfc1,
                          const float* __restrict__ bfc1, const float* __restrict__ Wfc2,
                          const float* __restrict__ bfc2, float* __restrict__ out) {
    __shared__ float gs[128];
    __shared__ float red0[256], red1[256];
    int b = blockIdx.x, tid = threadIdx.x;
    if (tid < 128) gs[tid] = g[b * 128 + tid];
    __syncthreads();
    float h0 = bfc1[tid], h1 = bfc1[tid + 256];
    for (int k = 0; k < 128; ++k) {
        float gv = gs[k];
        h0 += gv * Wfc1[k * 512 + tid];
        h1 += gv * Wfc1[k * 512 + tid + 256];
    }
    h0 = fmaxf(h0, 0.f); h1 = fmaxf(h1, 0.f);
    red0[tid] = h0 * Wfc2[tid * 2 + 0] + h1 * Wfc2[(tid + 256) * 2 + 0];
    red1[tid] = h0 * Wfc2[tid * 2 + 1] + h1 * Wfc2[(tid + 256) * 2 + 1];
    __syncthreads();
    for (int s = 128; s > 0; s >>= 1) {
        if (tid < s) { red0[tid] += red0[tid + s]; red1[tid] += red1[tid + s]; }
        __syncthreads();
    }
    if (tid == 0) {
        float L0 = red0[0] + bfc2[0], L1 = red1[0] + bfc2[1];
        float m = fmaxf(L0, L1);
        float e0 = expf(L0 - m), e1 = expf(L1 - m);
        float inv = 1.f / (e0 + e1);
        out[b * 2 + 0] = e0 * inv;
        out[b * 2 + 1] = e1 * inv;
    }
}

extern "C" void kernel_launch(void* const* d_in, const int* in_sizes, int n_in,
                              void* d_out, int out_size, void* d_ws, size_t ws_size,
                              hipStream_t stream) {
    const float* x     = (const float*)d_in[0];
    const int*   ei    = (const int*)d_in[1];
    const float* ew    = (const float*)d_in[2];
    const int*   batch = (const int*)d_in[3];
    const float* W1    = (const float*)d_in[4];
    const float* b1    = (const float*)d_in[5];
    const float* W2    = (const float*)d_in[6];
    const float* b2    = (const float*)d_in[7];
    const float* W3    = (const float*)d_in[8];
    const float* b3    = (const float*)d_in[9];
    const float* Wfc1  = (const float*)d_in[10];
    const float* bfc1  = (const float*)d_in[11];
    const float* Wfc2  = (const float*)d_in[12];
    const float* bfc2  = (const float*)d_in[13];

    const int N = in_sizes[3];      // 100000
    const int E = in_sizes[2];      // 1600000
    const int* row = ei;
    const int* col = ei + E;

    char* ws = (char*)d_ws;
    float* dinv      = (float*)ws; ws += align256((size_t)N * 4);
    int*   count     = (int*)ws;   ws += align256((size_t)N * 4);
    int*   offs      = (int*)ws;   ws += align256((size_t)(N + 1) * 4);
    int*   perm_row  = (int*)ws;   ws += align256((size_t)E * 4);
    float* perm_norm = (float*)ws; ws += align256((size_t)E * 4);
    float* bufA      = (float*)ws; ws += align256((size_t)N * 128 * 4);  // agg
    float* bufB      = (float*)ws; ws += align256((size_t)N * 128 * 4);  // H (prev layer)
    float* g         = (float*)ws; ws += align256((size_t)512 * 128 * 4);

    const int B = 256;

    // --- gcn_norm + CSR build ---
    hipMemsetAsync(dinv, 0, (size_t)N * 4, stream);
    hipMemsetAsync(count, 0, (size_t)N * 4, stream);
    deg_count_kernel<<<cdiv(E, B), B, 0, stream>>>(col, ew, dinv, count, E);
    dinv_kernel<<<cdiv(N, B), B, 0, stream>>>(dinv, N);
    scan_kernel<<<1, 1024, 0, stream>>>(count, offs, N);
    fill_kernel<<<cdiv(E, B), B, 0, stream>>>(row, col, ew, dinv, offs, count,
                                              perm_row, perm_norm, E);

    const long npair_thr = ((long)(N + 1) / 2);

    // --- conv1: agg = A*x (40-wide), H1 = relu(agg@W1 + b1) -> bufB ---
    gather_kernel<40><<<cdiv((long)N * 10, B), B, 0, stream>>>(
        offs, perm_row, perm_norm, x, dinv, bufA, N);
    gemm_kernel<40, 40, false><<<cdiv(npair_thr * 10, B), B, 0, stream>>>(
        bufA, W1, b1, bufB, nullptr, nullptr, N);

    // --- conv2: agg = A*H1 (40-wide), H2 = relu(agg@W2 + b2) -> bufB ---
    gather_kernel<40><<<cdiv((long)N * 10, B), B, 0, stream>>>(
        offs, perm_row, perm_norm, bufB, dinv, bufA, N);
    gemm_kernel<40, 80, false><<<cdiv(npair_thr * 20, B), B, 0, stream>>>(
        bufA, W2, b2, bufB, nullptr, nullptr, N);

    // --- conv3: agg = A*H2 (80-wide), pool(relu(agg@W3 + b3)) -> g directly ---
    gather_kernel<80><<<cdiv((long)N * 20, B), B, 0, stream>>>(
        offs, perm_row, perm_norm, bufB, dinv, bufA, N);
    hipMemsetAsync(g, 0, (size_t)512 * 128 * 4, stream);
    gemm_kernel<80, 128, true><<<cdiv(npair_thr * 32, B), B, 0, stream>>>(
        bufA, W3, b3, nullptr, batch, (unsigned int*)g, N);

    // --- MLP + softmax ---
    fc_kernel<<<512, 256, 0, stream>>>(g, Wfc1, bfc1, Wfc2, bfc2, (float*)d_out);
}

// Round 5
// 581.988 us; speedup vs baseline: 10.5128x; 1.2133x over previous
//
#include <hip/hip_runtime.h>

// ---------------------------------------------------------------------------
// GCNnet: 3x GCNConv (40->40->80->128) + global max pool + MLP(128->512->2) + softmax
// N=100000 nodes, E=1600000 edges, G=512 graphs.
// Round 4:
//  - deg+count -> ONE packed u64 atomic per edge: (1<<40)|round(w*2^24).
//    Returned old value >> 40 = per-edge rank (free). Halves atomic traffic.
//  - fill: NO atomics (pos = offs[c] + rank[e]); perm stored as int2
//    {row, norm_bits} -> one 8B scattered store per edge.
//  - scan: shuffle-based (3 barriers/chunk vs ~20), fuses dinv computation.
//  - rank[] aliases bufA (dead before gather1) -> no extra ws footprint.
// ---------------------------------------------------------------------------

static inline int cdiv(long a, int b) { return (int)((a + b - 1) / b); }
static inline size_t align256(size_t x) { return (x + 255) & ~(size_t)255; }

#define FXSCALE 16777216.0f           // 2^24
#define FXMASK  ((1ULL << 40) - 1)

// one u64 atomic per edge: high 24 bits count, low 40 bits fixed-point weight sum.
// old >> 40 = this edge's rank within its destination segment.
__global__ void deg_count_kernel(const int* __restrict__ col, const float* __restrict__ w,
                                 unsigned long long* __restrict__ packed,
                                 int* __restrict__ rank, int E) {
    int e = blockIdx.x * blockDim.x + threadIdx.x;
    if (e >= E) return;
    int c = col[e];
    unsigned long long fx = (unsigned long long)llrintf(w[e] * FXSCALE);
    unsigned long long old = atomicAdd(&packed[c], (1ULL << 40) | fx);
    rank[e] = (int)(old >> 40);
}

// exclusive scan of counts (packed>>40) -> offs[N+1]; also writes dinv.
// 1024 threads, 4 elems/thread, wave-shuffle scan (3 barriers per 4096 chunk).
__global__ void scan_kernel(const unsigned long long* __restrict__ packed,
                            int* __restrict__ offs, float* __restrict__ dinv, int N) {
    __shared__ int wsum[16];
    __shared__ int carry;
    int tid = threadIdx.x;
    int lane = tid & 63, wid = tid >> 6;
    if (tid == 0) carry = 0;
    __syncthreads();
    for (int base = 0; base < N; base += 4096) {
        int i0 = base + tid * 4;
        int v0 = 0, v1 = 0, v2 = 0, v3 = 0;
#define LOADI(k, vk) { int i = i0 + k; if (i < N) { \
            unsigned long long p = packed[i]; vk = (int)(p >> 40); \
            float deg = (float)(p & FXMASK) * (1.0f / FXSCALE); \
            dinv[i] = rsqrtf(deg + 1.0f); } }
        LOADI(0, v0) LOADI(1, v1) LOADI(2, v2) LOADI(3, v3)
#undef LOADI
        int sum = v0 + v1 + v2 + v3;
        int incl = sum;
#pragma unroll
        for (int off = 1; off < 64; off <<= 1) {
            int t = __shfl_up(incl, off, 64);
            if (lane >= off) incl += t;
        }
        if (lane == 63) wsum[wid] = incl;
        __syncthreads();
        if (wid == 0 && lane < 16) {
            int v = wsum[lane];
            int ic = v;
#pragma unroll
            for (int off = 1; off < 16; off <<= 1) {
                int t = __shfl_up(ic, off, 64);
                if (lane >= off) ic += t;
            }
            wsum[lane] = ic - v;   // exclusive
        }
        __syncthreads();
        int pre = carry + wsum[wid] + (incl - sum);
        if (i0 + 0 < N) offs[i0 + 0] = pre;
        if (i0 + 1 < N) offs[i0 + 1] = pre + v0;
        if (i0 + 2 < N) offs[i0 + 2] = pre + v0 + v1;
        if (i0 + 3 < N) offs[i0 + 3] = pre + v0 + v1 + v2;
        __syncthreads();
        if (tid == 1023) carry += wsum[15] + incl;
    }
    __syncthreads();
    if (tid == 1023) offs[N] = carry;
}

// CSR fill, atomic-free: pos = offs[col] + rank; perm = {row, norm bits} (8B store)
__global__ void fill_kernel(const int* __restrict__ row, const int* __restrict__ col,
                            const float* __restrict__ w, const int* __restrict__ rank,
                            const float* __restrict__ dinv, const int* __restrict__ offs,
                            int2* __restrict__ perm, int E) {
    int e = blockIdx.x * blockDim.x + threadIdx.x;
    if (e >= E) return;
    int r = row[e], c = col[e];
    int pos = offs[c] + rank[e];
    float nm = dinv[r] * w[e] * dinv[c];
    perm[pos] = make_int2(r, __float_as_int(nm));
}

// agg[d] = sum_{e: col=d} H[row_e]*norm_e + dinv[d]^2*H[d]
// thread = (node, 4 feats); 4-edge unroll -> 4 independent load chains
template<int F>
__global__ void gather_kernel(const int* __restrict__ offs, const int2* __restrict__ perm,
                              const float* __restrict__ H, const float* __restrict__ dinv,
                              float* __restrict__ agg, int N) {
    constexpr int TPN = F / 4;
    int idx = blockIdx.x * blockDim.x + threadIdx.x;
    int node = idx / TPN, q = idx % TPN;
    if (node >= N) return;
    int s = offs[node], e = offs[node + 1];
    float4 a0 = make_float4(0.f, 0.f, 0.f, 0.f);
    float4 a1 = make_float4(0.f, 0.f, 0.f, 0.f);
    int j = s;
    for (; j + 4 <= e; j += 4) {
        int2 p0 = perm[j + 0], p1 = perm[j + 1], p2 = perm[j + 2], p3 = perm[j + 3];
        float m0 = __int_as_float(p0.y), m1 = __int_as_float(p1.y);
        float m2 = __int_as_float(p2.y), m3 = __int_as_float(p3.y);
        float4 v0 = *(const float4*)(H + (long)p0.x * F + q * 4);
        float4 v1 = *(const float4*)(H + (long)p1.x * F + q * 4);
        float4 v2 = *(const float4*)(H + (long)p2.x * F + q * 4);
        float4 v3 = *(const float4*)(H + (long)p3.x * F + q * 4);
        a0.x += v0.x * m0; a0.y += v0.y * m0; a0.z += v0.z * m0; a0.w += v0.w * m0;
        a1.x += v1.x * m1; a1.y += v1.y * m1; a1.z += v1.z * m1; a1.w += v1.w * m1;
        a0.x += v2.x * m2; a0.y += v2.y * m2; a0.z += v2.z * m2; a0.w += v2.w * m2;
        a1.x += v3.x * m3; a1.y += v3.y * m3; a1.z += v3.z * m3; a1.w += v3.w * m3;
    }
    for (; j < e; ++j) {
        int2 p = perm[j];
        float nm = __int_as_float(p.y);
        float4 v = *(const float4*)(H + (long)p.x * F + q * 4);
        a0.x += v.x * nm; a0.y += v.y * nm; a0.z += v.z * nm; a0.w += v.w * nm;
    }
    float di = dinv[node], d2 = di * di;
    const float4 sv = *(const float4*)(H + (long)node * F + q * 4);
    float4 o = make_float4(a0.x + a1.x + d2 * sv.x, a0.y + a1.y + d2 * sv.y,
                           a0.z + a1.z + d2 * sv.z, a0.w + a1.w + d2 * sv.w);
    *(float4*)(agg + (long)node * F + q * 4) = o;
}

// out[N,FOUT] = relu(X[N,K] @ W[K,FOUT] + bias); thread = (2 nodes, 4 feats), W in LDS.
// FUSE_POOL: hierarchical max-pool — 2-graph LDS window (batch sorted), then
// zero-skipping global atomicMax flush; fallback direct atomics if rel >= 2.
template<int K, int FOUT, bool FUSE_POOL>
__global__ __launch_bounds__(256)
void gemm_kernel(const float* __restrict__ X, const float* __restrict__ W,
                 const float* __restrict__ bias, float* __restrict__ out,
                 const int* __restrict__ batch, unsigned int* __restrict__ g, int N) {
    constexpr int TPP = FOUT / 4;          // threads per node-pair
    constexpr int NPB = 2 * (256 / TPP);   // nodes per block
    __shared__ float ws[K * FOUT];
    __shared__ unsigned int gma[FUSE_POOL ? 2 * FOUT : 1];
    __shared__ int gfirst;
    for (int i = threadIdx.x; i < K * FOUT; i += 256) ws[i] = W[i];
    if (FUSE_POOL) {
        if (threadIdx.x == 0) gfirst = batch[min((int)(blockIdx.x * NPB), N - 1)];
        for (int i = threadIdx.x; i < 2 * FOUT; i += 256) gma[i] = 0u;
    }
    __syncthreads();

    int idx = blockIdx.x * 256 + threadIdx.x;
    int p = idx / TPP, q = idx % TPP;
    int n0 = p * 2;
    bool valid = n0 < N;
    bool has1 = (n0 + 1) < N;
    if (!FUSE_POOL && !valid) return;   // no later barriers on this path
    int cn0 = valid ? n0 : 0;
    int cn1 = has1 ? (n0 + 1) : cn0;
    const float4* xr0 = (const float4*)(X + (long)cn0 * K);
    const float4* xr1 = (const float4*)(X + (long)cn1 * K);
    const float* wq = ws + q * 4;
    float4 a0 = make_float4(0.f, 0.f, 0.f, 0.f);
    float4 a1 = make_float4(0.f, 0.f, 0.f, 0.f);
#pragma unroll 4
    for (int i = 0; i < K / 4; ++i) {
        float4 x0 = xr0[i];
        float4 x1 = xr1[i];
        const float* xx0 = (const float*)&x0;
        const float* xx1 = (const float*)&x1;
#pragma unroll
        for (int j = 0; j < 4; ++j) {
            float4 wv = *(const float4*)(wq + (i * 4 + j) * FOUT);
            float v0 = xx0[j], v1 = xx1[j];
            a0.x += v0 * wv.x; a0.y += v0 * wv.y; a0.z += v0 * wv.z; a0.w += v0 * wv.w;
            a1.x += v1 * wv.x; a1.y += v1 * wv.y; a1.z += v1 * wv.z; a1.w += v1 * wv.w;
        }
    }
    float4 bv = *(const float4*)(bias + q * 4);
    a0.x = fmaxf(a0.x + bv.x, 0.f); a0.y = fmaxf(a0.y + bv.y, 0.f);
    a0.z = fmaxf(a0.z + bv.z, 0.f); a0.w = fmaxf(a0.w + bv.w, 0.f);
    a1.x = fmaxf(a1.x + bv.x, 0.f); a1.y = fmaxf(a1.y + bv.y, 0.f);
    a1.z = fmaxf(a1.z + bv.z, 0.f); a1.w = fmaxf(a1.w + bv.w, 0.f);

    if (!FUSE_POOL) {
        *(float4*)(out + (long)n0 * FOUT + q * 4) = a0;
        if (has1) *(float4*)(out + (long)(n0 + 1) * FOUT + q * 4) = a1;
        return;
    }

    // ---- hierarchical pool ----
    auto push4 = [&](const float4& a, int node) {
        unsigned int bx = __float_as_uint(a.x), by = __float_as_uint(a.y);
        unsigned int bz = __float_as_uint(a.z), bw = __float_as_uint(a.w);
        int rel = batch[node] - gfirst;
        if (rel < 2) {
            unsigned int* d = gma + rel * FOUT + q * 4;
            atomicMax(d + 0, bx); atomicMax(d + 1, by);
            atomicMax(d + 2, bz); atomicMax(d + 3, bw);
        } else {
            unsigned int* d = g + (long)batch[node] * FOUT + q * 4;
            atomicMax(d + 0, bx); atomicMax(d + 1, by);
            atomicMax(d + 2, bz); atomicMax(d + 3, bw);
        }
    };
    if (valid) {
        push4(a0, n0);
        if (has1) push4(a1, n0 + 1);
    }
    __syncthreads();
    for (int i = threadIdx.x; i < 2 * FOUT; i += 256) {
        unsigned int v = gma[i];
        if (v) atomicMax(&g[(long)(gfirst + i / FOUT) * FOUT + (i % FOUT)], v);
    }
}

// one block per graph: relu(g@Wfc1+bfc1) @ Wfc2 + bfc2 -> softmax
__global__ void fc_kernel(const float* __restrict__ g, const float* __restrict__ Wfc1,
                          const float* __restrict__ bfc1, const float* __restrict__ Wfc2,
                          const float* __restrict__ bfc2, float* __restrict__ out) {
    __shared__ float gs[128];
    __shared__ float red0[256], red1[256];
    int b = blockIdx.x, tid = threadIdx.x;
    if (tid < 128) gs[tid] = g[b * 128 + tid];
    __syncthreads();
    float h0 = bfc1[tid], h1 = bfc1[tid + 256];
    for (int k = 0; k < 128; ++k) {
        float gv = gs[k];
        h0 += gv * Wfc1[k * 512 + tid];
        h1 += gv * Wfc1[k * 512 + tid + 256];
    }
    h0 = fmaxf(h0, 0.f); h1 = fmaxf(h1, 0.f);
    red0[tid] = h0 * Wfc2[tid * 2 + 0] + h1 * Wfc2[(tid + 256) * 2 + 0];
    red1[tid] = h0 * Wfc2[tid * 2 + 1] + h1 * Wfc2[(tid + 256) * 2 + 1];
    __syncthreads();
    for (int s = 128; s > 0; s >>= 1) {
        if (tid < s) { red0[tid] += red0[tid + s]; red1[tid] += red1[tid + s]; }
        __syncthreads();
    }
    if (tid == 0) {
        float L0 = red0[0] + bfc2[0], L1 = red1[0] + bfc2[1];
        float m = fmaxf(L0, L1);
        float e0 = expf(L0 - m), e1 = expf(L1 - m);
        float inv = 1.f / (e0 + e1);
        out[b * 2 + 0] = e0 * inv;
        out[b * 2 + 1] = e1 * inv;
    }
}

extern "C" void kernel_launch(void* const* d_in, const int* in_sizes, int n_in,
                              void* d_out, int out_size, void* d_ws, size_t ws_size,
                              hipStream_t stream) {
    const float* x     = (const float*)d_in[0];
    const int*   ei    = (const int*)d_in[1];
    const float* ew    = (const float*)d_in[2];
    const int*   batch = (const int*)d_in[3];
    const float* W1    = (const float*)d_in[4];
    const float* b1    = (const float*)d_in[5];
    const float* W2    = (const float*)d_in[6];
    const float* b2    = (const float*)d_in[7];
    const float* W3    = (const float*)d_in[8];
    const float* b3    = (const float*)d_in[9];
    const float* Wfc1  = (const float*)d_in[10];
    const float* bfc1  = (const float*)d_in[11];
    const float* Wfc2  = (const float*)d_in[12];
    const float* bfc2  = (const float*)d_in[13];

    const int N = in_sizes[3];      // 100000
    const int E = in_sizes[2];      // 1600000
    const int* row = ei;
    const int* col = ei + E;

    char* ws = (char*)d_ws;
    float* dinv   = (float*)ws;              ws += align256((size_t)N * 4);
    unsigned long long* packed = (unsigned long long*)ws; ws += align256((size_t)N * 8);
    int*   offs   = (int*)ws;                ws += align256((size_t)(N + 1) * 4);
    int2*  perm   = (int2*)ws;               ws += align256((size_t)E * 8);
    float* bufA   = (float*)ws;              ws += align256((size_t)N * 128 * 4);  // agg
    float* bufB   = (float*)ws;              ws += align256((size_t)N * 128 * 4);  // H (prev)
    float* g      = (float*)ws;              ws += align256((size_t)512 * 128 * 4);
    int*   rank   = (int*)bufA;   // rank[E] (6.4MB) aliases bufA — dead before gather1

    const int B = 256;

    // --- gcn_norm + CSR build ---
    hipMemsetAsync(packed, 0, (size_t)N * 8, stream);
    deg_count_kernel<<<cdiv(E, B), B, 0, stream>>>(col, ew, packed, rank, E);
    scan_kernel<<<1, 1024, 0, stream>>>(packed, offs, dinv, N);
    fill_kernel<<<cdiv(E, B), B, 0, stream>>>(row, col, ew, rank, dinv, offs, perm, E);

    const long npair_thr = ((long)(N + 1) / 2);

    // --- conv1: agg = A*x (40-wide), H1 = relu(agg@W1 + b1) -> bufB ---
    gather_kernel<40><<<cdiv((long)N * 10, B), B, 0, stream>>>(
        offs, perm, x, dinv, bufA, N);
    gemm_kernel<40, 40, false><<<cdiv(npair_thr * 10, B), B, 0, stream>>>(
        bufA, W1, b1, bufB, nullptr, nullptr, N);

    // --- conv2: agg = A*H1 (40-wide), H2 = relu(agg@W2 + b2) -> bufB ---
    gather_kernel<40><<<cdiv((long)N * 10, B), B, 0, stream>>>(
        offs, perm, bufB, dinv, bufA, N);
    gemm_kernel<40, 80, false><<<cdiv(npair_thr * 20, B), B, 0, stream>>>(
        bufA, W2, b2, bufB, nullptr, nullptr, N);

    // --- conv3: agg = A*H2 (80-wide), pool(relu(agg@W3 + b3)) -> g directly ---
    gather_kernel<80><<<cdiv((long)N * 20, B), B, 0, stream>>>(
        offs, perm, bufB, dinv, bufA, N);
    hipMemsetAsync(g, 0, (size_t)512 * 128 * 4, stream);
    gemm_kernel<80, 128, true><<<cdiv(npair_thr * 32, B), B, 0, stream>>>(
        bufA, W3, b3, nullptr, batch, (unsigned int*)g, N);

    // --- MLP + softmax ---
    fc_kernel<<<512, 256, 0, stream>>>(g, Wfc1, bfc1, Wfc2, bfc2, (float*)d_out);
}

// Round 6
// 519.640 us; speedup vs baseline: 11.7742x; 1.1200x over previous
//
#include <hip/hip_runtime.h>

// ---------------------------------------------------------------------------
// GCNnet: 3x GCNConv (40->40->80->128) + global max pool + MLP(128->512->2) + softmax
// N=100000 nodes, E=1600000 edges, G=512 graphs.
// Round 5: bf16 gather paths.
//  - H1/H2 stored bf16 (RNE) from GEMM epilogue; x converted to bf16 once.
//  - gather reads ushort4 (4 feats / 8 B per thread) -> bytes/edge halved AND
//    L2-resident fraction doubled (H2 32->16 MB vs 4 MB/XCD L2).
//  - agg stays f32 (sequential; GEMM input precision). Pool/FC unchanged.
//  - Harness compares in bf16 space (thr 1.04e-2); bf16 H adds ~1e-3 at out.
// ---------------------------------------------------------------------------

static inline int cdiv(long a, int b) { return (int)((a + b - 1) / b); }
static inline size_t align256(size_t x) { return (x + 255) & ~(size_t)255; }

#define FXSCALE 16777216.0f           // 2^24
#define FXMASK  ((1ULL << 40) - 1)

__device__ __forceinline__ float bf2f(unsigned short u) {
    return __uint_as_float(((unsigned int)u) << 16);
}
__device__ __forceinline__ unsigned short f2bf(float f) {   // round-nearest-even
    unsigned int u = __float_as_uint(f);
    return (unsigned short)((u + 0x7FFFu + ((u >> 16) & 1u)) >> 16);
}

// one u64 atomic per edge: high 24 bits count, low 40 bits fixed-point weight sum.
// old >> 40 = this edge's rank within its destination segment.
__global__ void deg_count_kernel(const int* __restrict__ col, const float* __restrict__ w,
                                 unsigned long long* __restrict__ packed,
                                 int* __restrict__ rank, int E) {
    int e = blockIdx.x * blockDim.x + threadIdx.x;
    if (e >= E) return;
    int c = col[e];
    unsigned long long fx = (unsigned long long)llrintf(w[e] * FXSCALE);
    unsigned long long old = atomicAdd(&packed[c], (1ULL << 40) | fx);
    rank[e] = (int)(old >> 40);
}

// exclusive scan of counts (packed>>40) -> offs[N+1]; also writes dinv.
__global__ void scan_kernel(const unsigned long long* __restrict__ packed,
                            int* __restrict__ offs, float* __restrict__ dinv, int N) {
    __shared__ int wsum[16];
    __shared__ int carry;
    int tid = threadIdx.x;
    int lane = tid & 63, wid = tid >> 6;
    if (tid == 0) carry = 0;
    __syncthreads();
    for (int base = 0; base < N; base += 4096) {
        int i0 = base + tid * 4;
        int v0 = 0, v1 = 0, v2 = 0, v3 = 0;
#define LOADI(k, vk) { int i = i0 + k; if (i < N) { \
            unsigned long long p = packed[i]; vk = (int)(p >> 40); \
            float deg = (float)(p & FXMASK) * (1.0f / FXSCALE); \
            dinv[i] = rsqrtf(deg + 1.0f); } }
        LOADI(0, v0) LOADI(1, v1) LOADI(2, v2) LOADI(3, v3)
#undef LOADI
        int sum = v0 + v1 + v2 + v3;
        int incl = sum;
#pragma unroll
        for (int off = 1; off < 64; off <<= 1) {
            int t = __shfl_up(incl, off, 64);
            if (lane >= off) incl += t;
        }
        if (lane == 63) wsum[wid] = incl;
        __syncthreads();
        if (wid == 0 && lane < 16) {
            int v = wsum[lane];
            int ic = v;
#pragma unroll
            for (int off = 1; off < 16; off <<= 1) {
                int t = __shfl_up(ic, off, 64);
                if (lane >= off) ic += t;
            }
            wsum[lane] = ic - v;   // exclusive
        }
        __syncthreads();
        int pre = carry + wsum[wid] + (incl - sum);
        if (i0 + 0 < N) offs[i0 + 0] = pre;
        if (i0 + 1 < N) offs[i0 + 1] = pre + v0;
        if (i0 + 2 < N) offs[i0 + 2] = pre + v0 + v1;
        if (i0 + 3 < N) offs[i0 + 3] = pre + v0 + v1 + v2;
        __syncthreads();
        if (tid == 1023) carry += wsum[15] + incl;
    }
    __syncthreads();
    if (tid == 1023) offs[N] = carry;
}

// CSR fill, atomic-free: pos = offs[col] + rank; perm = {row, norm bits} (8B store)
__global__ void fill_kernel(const int* __restrict__ row, const int* __restrict__ col,
                            const float* __restrict__ w, const int* __restrict__ rank,
                            const float* __restrict__ dinv, const int* __restrict__ offs,
                            int2* __restrict__ perm, int E) {
    int e = blockIdx.x * blockDim.x + threadIdx.x;
    if (e >= E) return;
    int r = row[e], c = col[e];
    int pos = offs[c] + rank[e];
    float nm = dinv[r] * w[e] * dinv[c];
    perm[pos] = make_int2(r, __float_as_int(nm));
}

// f32 -> bf16 bulk convert (n divisible by 4)
__global__ void f2bf_kernel(const float* __restrict__ in, ushort* __restrict__ out, int n4) {
    int i = blockIdx.x * blockDim.x + threadIdx.x;
    if (i >= n4) return;
    float4 v = ((const float4*)in)[i];
    ((ushort4*)out)[i] = make_ushort4(f2bf(v.x), f2bf(v.y), f2bf(v.z), f2bf(v.w));
}

// agg[d] = sum_{e: col=d} H[row_e]*norm_e + dinv[d]^2*H[d]   (H in bf16)
// thread = (node, 4 feats); 4-edge unroll -> 4 independent load chains
template<int F>
__global__ void gather_kernel(const int* __restrict__ offs, const int2* __restrict__ perm,
                              const ushort* __restrict__ H, const float* __restrict__ dinv,
                              float* __restrict__ agg, int N) {
    constexpr int TPN = F / 4;
    int idx = blockIdx.x * blockDim.x + threadIdx.x;
    int node = idx / TPN, q = idx % TPN;
    if (node >= N) return;
    int s = offs[node], e = offs[node + 1];
    float4 a0 = make_float4(0.f, 0.f, 0.f, 0.f);
    float4 a1 = make_float4(0.f, 0.f, 0.f, 0.f);
    int j = s;
    for (; j + 4 <= e; j += 4) {
        int2 p0 = perm[j + 0], p1 = perm[j + 1], p2 = perm[j + 2], p3 = perm[j + 3];
        float m0 = __int_as_float(p0.y), m1 = __int_as_float(p1.y);
        float m2 = __int_as_float(p2.y), m3 = __int_as_float(p3.y);
        ushort4 u0 = *(const ushort4*)(H + (long)p0.x * F + q * 4);
        ushort4 u1 = *(const ushort4*)(H + (long)p1.x * F + q * 4);
        ushort4 u2 = *(const ushort4*)(H + (long)p2.x * F + q * 4);
        ushort4 u3 = *(const ushort4*)(H + (long)p3.x * F + q * 4);
        a0.x += bf2f(u0.x) * m0; a0.y += bf2f(u0.y) * m0;
        a0.z += bf2f(u0.z) * m0; a0.w += bf2f(u0.w) * m0;
        a1.x += bf2f(u1.x) * m1; a1.y += bf2f(u1.y) * m1;
        a1.z += bf2f(u1.z) * m1; a1.w += bf2f(u1.w) * m1;
        a0.x += bf2f(u2.x) * m2; a0.y += bf2f(u2.y) * m2;
        a0.z += bf2f(u2.z) * m2; a0.w += bf2f(u2.w) * m2;
        a1.x += bf2f(u3.x) * m3; a1.y += bf2f(u3.y) * m3;
        a1.z += bf2f(u3.z) * m3; a1.w += bf2f(u3.w) * m3;
    }
    for (; j < e; ++j) {
        int2 p = perm[j];
        float nm = __int_as_float(p.y);
        ushort4 u = *(const ushort4*)(H + (long)p.x * F + q * 4);
        a0.x += bf2f(u.x) * nm; a0.y += bf2f(u.y) * nm;
        a0.z += bf2f(u.z) * nm; a0.w += bf2f(u.w) * nm;
    }
    float di = dinv[node], d2 = di * di;
    ushort4 su = *(const ushort4*)(H + (long)node * F + q * 4);
    float4 o = make_float4(a0.x + a1.x + d2 * bf2f(su.x), a0.y + a1.y + d2 * bf2f(su.y),
                           a0.z + a1.z + d2 * bf2f(su.z), a0.w + a1.w + d2 * bf2f(su.w));
    *(float4*)(agg + (long)node * F + q * 4) = o;
}

// out[N,FOUT] = relu(X[N,K] @ W[K,FOUT] + bias); thread = (2 nodes, 4 feats), W in LDS.
// BF16OUT: store ushort4 bf16. FUSE_POOL: hierarchical max-pool (2-graph LDS
// window, zero-skipping flush; direct global atomics if rel >= 2).
template<int K, int FOUT, bool FUSE_POOL, bool BF16OUT>
__global__ __launch_bounds__(256)
void gemm_kernel(const float* __restrict__ X, const float* __restrict__ W,
                 const float* __restrict__ bias, void* __restrict__ out,
                 const int* __restrict__ batch, unsigned int* __restrict__ g, int N) {
    constexpr int TPP = FOUT / 4;          // threads per node-pair
    constexpr int NPB = 2 * (256 / TPP);   // nodes per block
    __shared__ float ws[K * FOUT];
    __shared__ unsigned int gma[FUSE_POOL ? 2 * FOUT : 1];
    __shared__ int gfirst;
    for (int i = threadIdx.x; i < K * FOUT; i += 256) ws[i] = W[i];
    if (FUSE_POOL) {
        if (threadIdx.x == 0) gfirst = batch[min((int)(blockIdx.x * NPB), N - 1)];
        for (int i = threadIdx.x; i < 2 * FOUT; i += 256) gma[i] = 0u;
    }
    __syncthreads();

    int idx = blockIdx.x * 256 + threadIdx.x;
    int p = idx / TPP, q = idx % TPP;
    int n0 = p * 2;
    bool valid = n0 < N;
    bool has1 = (n0 + 1) < N;
    if (!FUSE_POOL && !valid) return;   // no later barriers on this path
    int cn0 = valid ? n0 : 0;
    int cn1 = has1 ? (n0 + 1) : cn0;
    const float4* xr0 = (const float4*)(X + (long)cn0 * K);
    const float4* xr1 = (const float4*)(X + (long)cn1 * K);
    const float* wq = ws + q * 4;
    float4 a0 = make_float4(0.f, 0.f, 0.f, 0.f);
    float4 a1 = make_float4(0.f, 0.f, 0.f, 0.f);
#pragma unroll 4
    for (int i = 0; i < K / 4; ++i) {
        float4 x0 = xr0[i];
        float4 x1 = xr1[i];
        const float* xx0 = (const float*)&x0;
        const float* xx1 = (const float*)&x1;
#pragma unroll
        for (int j = 0; j < 4; ++j) {
            float4 wv = *(const float4*)(wq + (i * 4 + j) * FOUT);
            float v0 = xx0[j], v1 = xx1[j];
            a0.x += v0 * wv.x; a0.y += v0 * wv.y; a0.z += v0 * wv.z; a0.w += v0 * wv.w;
            a1.x += v1 * wv.x; a1.y += v1 * wv.y; a1.z += v1 * wv.z; a1.w += v1 * wv.w;
        }
    }
    float4 bv = *(const float4*)(bias + q * 4);
    a0.x = fmaxf(a0.x + bv.x, 0.f); a0.y = fmaxf(a0.y + bv.y, 0.f);
    a0.z = fmaxf(a0.z + bv.z, 0.f); a0.w = fmaxf(a0.w + bv.w, 0.f);
    a1.x = fmaxf(a1.x + bv.x, 0.f); a1.y = fmaxf(a1.y + bv.y, 0.f);
    a1.z = fmaxf(a1.z + bv.z, 0.f); a1.w = fmaxf(a1.w + bv.w, 0.f);

    if (!FUSE_POOL) {
        if (BF16OUT) {
            ushort* ob = (ushort*)out;
            *(ushort4*)(ob + (long)n0 * FOUT + q * 4) =
                make_ushort4(f2bf(a0.x), f2bf(a0.y), f2bf(a0.z), f2bf(a0.w));
            if (has1)
                *(ushort4*)(ob + (long)(n0 + 1) * FOUT + q * 4) =
                    make_ushort4(f2bf(a1.x), f2bf(a1.y), f2bf(a1.z), f2bf(a1.w));
        } else {
            float* of = (float*)out;
            *(float4*)(of + (long)n0 * FOUT + q * 4) = a0;
            if (has1) *(float4*)(of + (long)(n0 + 1) * FOUT + q * 4) = a1;
        }
        return;
    }

    // ---- hierarchical pool ----
    auto push4 = [&](const float4& a, int node) {
        unsigned int bx = __float_as_uint(a.x), by = __float_as_uint(a.y);
        unsigned int bz = __float_as_uint(a.z), bw = __float_as_uint(a.w);
        int rel = batch[node] - gfirst;
        if (rel < 2) {
            unsigned int* d = gma + rel * FOUT + q * 4;
            atomicMax(d + 0, bx); atomicMax(d + 1, by);
            atomicMax(d + 2, bz); atomicMax(d + 3, bw);
        } else {
            unsigned int* d = g + (long)batch[node] * FOUT + q * 4;
            atomicMax(d + 0, bx); atomicMax(d + 1, by);
            atomicMax(d + 2, bz); atomicMax(d + 3, bw);
        }
    };
    if (valid) {
        push4(a0, n0);
        if (has1) push4(a1, n0 + 1);
    }
    __syncthreads();
    for (int i = threadIdx.x; i < 2 * FOUT; i += 256) {
        unsigned int v = gma[i];
        if (v) atomicMax(&g[(long)(gfirst + i / FOUT) * FOUT + (i % FOUT)], v);
    }
}

// one block per graph: relu(g@Wfc1+bfc1) @ Wfc2 + bfc2 -> softmax
__global__ void fc_kernel(const float* __restrict__ g, const float* __restrict__ Wfc1,
                          const float* __restrict__ bfc1, const float* __restrict__ Wfc2,
                          const float* __restrict__ bfc2, float* __restrict__ out) {
    __shared__ float gs[128];
    __shared__ float red0[256], red1[256];
    int b = blockIdx.x, tid = threadIdx.x;
    if (tid < 128) gs[tid] = g[b * 128 + tid];
    __syncthreads();
    float h0 = bfc1[tid], h1 = bfc1[tid + 256];
    for (int k = 0; k < 128; ++k) {
        float gv = gs[k];
        h0 += gv * Wfc1[k * 512 + tid];
        h1 += gv * Wfc1[k * 512 + tid + 256];
    }
    h0 = fmaxf(h0, 0.f); h1 = fmaxf(h1, 0.f);
    red0[tid] = h0 * Wfc2[tid * 2 + 0] + h1 * Wfc2[(tid + 256) * 2 + 0];
    red1[tid] = h0 * Wfc2[tid * 2 + 1] + h1 * Wfc2[(tid + 256) * 2 + 1];
    __syncthreads();
    for (int s = 128; s > 0; s >>= 1) {
        if (tid < s) { red0[tid] += red0[tid + s]; red1[tid] += red1[tid + s]; }
        __syncthreads();
    }
    if (tid == 0) {
        float L0 = red0[0] + bfc2[0], L1 = red1[0] + bfc2[1];
        float m = fmaxf(L0, L1);
        float e0 = expf(L0 - m), e1 = expf(L1 - m);
        float inv = 1.f / (e0 + e1);
        out[b * 2 + 0] = e0 * inv;
        out[b * 2 + 1] = e1 * inv;
    }
}

extern "C" void kernel_launch(void* const* d_in, const int* in_sizes, int n_in,
                              void* d_out, int out_size, void* d_ws, size_t ws_size,
                              hipStream_t stream) {
    const float* x     = (const float*)d_in[0];
    const int*   ei    = (const int*)d_in[1];
    const float* ew    = (const float*)d_in[2];
    const int*   batch = (const int*)d_in[3];
    const float* W1    = (const float*)d_in[4];
    const float* b1    = (const float*)d_in[5];
    const float* W2    = (const float*)d_in[6];
    const float* b2    = (const float*)d_in[7];
    const float* W3    = (const float*)d_in[8];
    const float* b3    = (const float*)d_in[9];
    const float* Wfc1  = (const float*)d_in[10];
    const float* bfc1  = (const float*)d_in[11];
    const float* Wfc2  = (const float*)d_in[12];
    const float* bfc2  = (const float*)d_in[13];

    const int N = in_sizes[3];      // 100000
    const int E = in_sizes[2];      // 1600000
    const int* row = ei;
    const int* col = ei + E;

    char* ws = (char*)d_ws;
    float* dinv   = (float*)ws;              ws += align256((size_t)N * 4);
    unsigned long long* packed = (unsigned long long*)ws; ws += align256((size_t)N * 8);
    int*   offs   = (int*)ws;                ws += align256((size_t)(N + 1) * 4);
    int2*  perm   = (int2*)ws;               ws += align256((size_t)E * 8);
    float* bufA   = (float*)ws;              ws += align256((size_t)N * 128 * 4);  // agg f32
    ushort* bufH  = (ushort*)ws;             ws += align256((size_t)N * 128 * 2);  // H bf16
    ushort* xbf   = (ushort*)ws;             ws += align256((size_t)N * 40 * 2);   // x bf16
    float* g      = (float*)ws;              ws += align256((size_t)512 * 128 * 4);
    int*   rank   = (int*)bufA;   // rank[E] (6.4MB) aliases bufA — dead before gather1

    const int B = 256;

    // --- gcn_norm + CSR build ---
    hipMemsetAsync(packed, 0, (size_t)N * 8, stream);
    deg_count_kernel<<<cdiv(E, B), B, 0, stream>>>(col, ew, packed, rank, E);
    scan_kernel<<<1, 1024, 0, stream>>>(packed, offs, dinv, N);
    fill_kernel<<<cdiv(E, B), B, 0, stream>>>(row, col, ew, rank, dinv, offs, perm, E);
    f2bf_kernel<<<cdiv((long)N * 10, B), B, 0, stream>>>(x, xbf, N * 10);

    const long npair_thr = ((long)(N + 1) / 2);

    // --- conv1: agg = A*x (40-wide bf16), H1 = relu(agg@W1 + b1) -> bufH (bf16) ---
    gather_kernel<40><<<cdiv((long)N * 10, B), B, 0, stream>>>(
        offs, perm, xbf, dinv, bufA, N);
    gemm_kernel<40, 40, false, true><<<cdiv(npair_thr * 10, B), B, 0, stream>>>(
        bufA, W1, b1, bufH, nullptr, nullptr, N);

    // --- conv2: agg = A*H1 (40-wide bf16), H2 = relu(agg@W2 + b2) -> bufH (bf16) ---
    gather_kernel<40><<<cdiv((long)N * 10, B), B, 0, stream>>>(
        offs, perm, bufH, dinv, bufA, N);
    gemm_kernel<40, 80, false, true><<<cdiv(npair_thr * 20, B), B, 0, stream>>>(
        bufA, W2, b2, bufH, nullptr, nullptr, N);

    // --- conv3: agg = A*H2 (80-wide bf16), pool(relu(agg@W3 + b3)) -> g ---
    gather_kernel<80><<<cdiv((long)N * 20, B), B, 0, stream>>>(
        offs, perm, bufH, dinv, bufA, N);
    hipMemsetAsync(g, 0, (size_t)512 * 128 * 4, stream);
    gemm_kernel<80, 128, true, false><<<cdiv(npair_thr * 32, B), B, 0, stream>>>(
        bufA, W3, b3, nullptr, batch, (unsigned int*)g, N);

    // --- MLP + softmax ---
    fc_kernel<<<512, 256, 0, stream>>>(g, Wfc1, bfc1, Wfc2, bfc2, (float*)d_out);
}

// Round 7
// 444.735 us; speedup vs baseline: 13.7573x; 1.1684x over previous
//
#include <hip/hip_runtime.h>

// ---------------------------------------------------------------------------
// GCNnet: 3x GCNConv (40->40->80->128) + global max pool + MLP(128->512->2) + softmax
// N=100000 nodes, E=1600000 edges, G=512 graphs.
// Round 6: single-block scan (78.7us, 0.17% occupancy) -> 3-phase multi-block
// scan (A: block sums + dinv; B: scan of block sums; C: local scan + offset).
// Everything else as Round 5 (bf16 gather paths, packed-u64 CSR build,
// hierarchical pool fusion, register-blocked GEMMs).
// ---------------------------------------------------------------------------

static inline int cdiv(long a, int b) { return (int)((a + b - 1) / b); }
static inline size_t align256(size_t x) { return (x + 255) & ~(size_t)255; }

#define FXSCALE 16777216.0f           // 2^24
#define FXMASK  ((1ULL << 40) - 1)
#define SCHUNK  1024                  // elements per scan block

__device__ __forceinline__ float bf2f(unsigned short u) {
    return __uint_as_float(((unsigned int)u) << 16);
}
__device__ __forceinline__ unsigned short f2bf(float f) {   // round-nearest-even
    unsigned int u = __float_as_uint(f);
    return (unsigned short)((u + 0x7FFFu + ((u >> 16) & 1u)) >> 16);
}

// one u64 atomic per edge: high 24 bits count, low 40 bits fixed-point weight sum.
// old >> 40 = this edge's rank within its destination segment.
__global__ void deg_count_kernel(const int* __restrict__ col, const float* __restrict__ w,
                                 unsigned long long* __restrict__ packed,
                                 int* __restrict__ rank, int E) {
    int e = blockIdx.x * blockDim.x + threadIdx.x;
    if (e >= E) return;
    int c = col[e];
    unsigned long long fx = (unsigned long long)llrintf(w[e] * FXSCALE);
    unsigned long long old = atomicAdd(&packed[c], (1ULL << 40) | fx);
    rank[e] = (int)(old >> 40);
}

// scan phase A: per-block count sums + dinv (256 thr x 4 elems = 1024/block)
__global__ void scanA_kernel(const unsigned long long* __restrict__ packed,
                             float* __restrict__ dinv, int* __restrict__ blockSums, int N) {
    __shared__ int wred[4];
    int tid = threadIdx.x, lane = tid & 63, wid = tid >> 6;
    int i0 = blockIdx.x * SCHUNK + tid * 4;
    int s = 0;
#pragma unroll
    for (int k = 0; k < 4; ++k) {
        int i = i0 + k;
        if (i < N) {
            unsigned long long p = packed[i];
            s += (int)(p >> 40);
            float deg = (float)(p & FXMASK) * (1.0f / FXSCALE);
            dinv[i] = rsqrtf(deg + 1.0f);
        }
    }
#pragma unroll
    for (int off = 32; off > 0; off >>= 1) s += __shfl_down(s, off, 64);
    if (lane == 0) wred[wid] = s;
    __syncthreads();
    if (tid == 0) blockSums[blockIdx.x] = wred[0] + wred[1] + wred[2] + wred[3];
}

// scan phase B: one block, exclusive scan of blockSums[nb] (nb <= 1024);
// writes total into offs[N].
__global__ void scanB_kernel(int* __restrict__ blockSums, int* __restrict__ offs,
                             int nb, int N) {
    __shared__ int wsum[16];
    int tid = threadIdx.x, lane = tid & 63, wid = tid >> 6;
    int v = (tid < nb) ? blockSums[tid] : 0;
    int incl = v;
#pragma unroll
    for (int off = 1; off < 64; off <<= 1) {
        int t = __shfl_up(incl, off, 64);
        if (lane >= off) incl += t;
    }
    if (lane == 63) wsum[wid] = incl;
    __syncthreads();
    if (wid == 0 && lane < 16) {
        int w = wsum[lane];
        int ic = w;
#pragma unroll
        for (int off = 1; off < 16; off <<= 1) {
            int t = __shfl_up(ic, off, 64);
            if (lane >= off) ic += t;
        }
        wsum[lane] = ic - w;   // exclusive
    }
    __syncthreads();
    if (tid < nb) blockSums[tid] = wsum[wid] + incl - v;   // exclusive prefix
    if (tid == 1023) offs[N] = wsum[15] + incl;            // grand total
}

// scan phase C: local exclusive scan + block offset -> offs
__global__ void scanC_kernel(const unsigned long long* __restrict__ packed,
                             const int* __restrict__ blockSums,
                             int* __restrict__ offs, int N) {
    __shared__ int wsum[4];
    int tid = threadIdx.x, lane = tid & 63, wid = tid >> 6;
    int i0 = blockIdx.x * SCHUNK + tid * 4;
    int v0 = 0, v1 = 0, v2 = 0, v3 = 0;
    if (i0 + 0 < N) v0 = (int)(packed[i0 + 0] >> 40);
    if (i0 + 1 < N) v1 = (int)(packed[i0 + 1] >> 40);
    if (i0 + 2 < N) v2 = (int)(packed[i0 + 2] >> 40);
    if (i0 + 3 < N) v3 = (int)(packed[i0 + 3] >> 40);
    int sum = v0 + v1 + v2 + v3;
    int incl = sum;
#pragma unroll
    for (int off = 1; off < 64; off <<= 1) {
        int t = __shfl_up(incl, off, 64);
        if (lane >= off) incl += t;
    }
    if (lane == 63) wsum[wid] = incl;
    __syncthreads();
    if (tid == 0) {
        int c = 0;
#pragma unroll
        for (int k = 0; k < 4; ++k) { int t = wsum[k]; wsum[k] = c; c += t; }
    }
    __syncthreads();
    int pre = blockSums[blockIdx.x] + wsum[wid] + (incl - sum);
    if (i0 + 0 < N) offs[i0 + 0] = pre;
    if (i0 + 1 < N) offs[i0 + 1] = pre + v0;
    if (i0 + 2 < N) offs[i0 + 2] = pre + v0 + v1;
    if (i0 + 3 < N) offs[i0 + 3] = pre + v0 + v1 + v2;
}

// CSR fill, atomic-free: pos = offs[col] + rank; perm = {row, norm bits} (8B store)
__global__ void fill_kernel(const int* __restrict__ row, const int* __restrict__ col,
                            const float* __restrict__ w, const int* __restrict__ rank,
                            const float* __restrict__ dinv, const int* __restrict__ offs,
                            int2* __restrict__ perm, int E) {
    int e = blockIdx.x * blockDim.x + threadIdx.x;
    if (e >= E) return;
    int r = row[e], c = col[e];
    int pos = offs[c] + rank[e];
    float nm = dinv[r] * w[e] * dinv[c];
    perm[pos] = make_int2(r, __float_as_int(nm));
}

// f32 -> bf16 bulk convert (n divisible by 4)
__global__ void f2bf_kernel(const float* __restrict__ in, ushort* __restrict__ out, int n4) {
    int i = blockIdx.x * blockDim.x + threadIdx.x;
    if (i >= n4) return;
    float4 v = ((const float4*)in)[i];
    ((ushort4*)out)[i] = make_ushort4(f2bf(v.x), f2bf(v.y), f2bf(v.z), f2bf(v.w));
}

// agg[d] = sum_{e: col=d} H[row_e]*norm_e + dinv[d]^2*H[d]   (H in bf16)
// thread = (node, 4 feats); 4-edge unroll -> 4 independent load chains
template<int F>
__global__ void gather_kernel(const int* __restrict__ offs, const int2* __restrict__ perm,
                              const ushort* __restrict__ H, const float* __restrict__ dinv,
                              float* __restrict__ agg, int N) {
    constexpr int TPN = F / 4;
    int idx = blockIdx.x * blockDim.x + threadIdx.x;
    int node = idx / TPN, q = idx % TPN;
    if (node >= N) return;
    int s = offs[node], e = offs[node + 1];
    float4 a0 = make_float4(0.f, 0.f, 0.f, 0.f);
    float4 a1 = make_float4(0.f, 0.f, 0.f, 0.f);
    int j = s;
    for (; j + 4 <= e; j += 4) {
        int2 p0 = perm[j + 0], p1 = perm[j + 1], p2 = perm[j + 2], p3 = perm[j + 3];
        float m0 = __int_as_float(p0.y), m1 = __int_as_float(p1.y);
        float m2 = __int_as_float(p2.y), m3 = __int_as_float(p3.y);
        ushort4 u0 = *(const ushort4*)(H + (long)p0.x * F + q * 4);
        ushort4 u1 = *(const ushort4*)(H + (long)p1.x * F + q * 4);
        ushort4 u2 = *(const ushort4*)(H + (long)p2.x * F + q * 4);
        ushort4 u3 = *(const ushort4*)(H + (long)p3.x * F + q * 4);
        a0.x += bf2f(u0.x) * m0; a0.y += bf2f(u0.y) * m0;
        a0.z += bf2f(u0.z) * m0; a0.w += bf2f(u0.w) * m0;
        a1.x += bf2f(u1.x) * m1; a1.y += bf2f(u1.y) * m1;
        a1.z += bf2f(u1.z) * m1; a1.w += bf2f(u1.w) * m1;
        a0.x += bf2f(u2.x) * m2; a0.y += bf2f(u2.y) * m2;
        a0.z += bf2f(u2.z) * m2; a0.w += bf2f(u2.w) * m2;
        a1.x += bf2f(u3.x) * m3; a1.y += bf2f(u3.y) * m3;
        a1.z += bf2f(u3.z) * m3; a1.w += bf2f(u3.w) * m3;
    }
    for (; j < e; ++j) {
        int2 p = perm[j];
        float nm = __int_as_float(p.y);
        ushort4 u = *(const ushort4*)(H + (long)p.x * F + q * 4);
        a0.x += bf2f(u.x) * nm; a0.y += bf2f(u.y) * nm;
        a0.z += bf2f(u.z) * nm; a0.w += bf2f(u.w) * nm;
    }
    float di = dinv[node], d2 = di * di;
    ushort4 su = *(const ushort4*)(H + (long)node * F + q * 4);
    float4 o = make_float4(a0.x + a1.x + d2 * bf2f(su.x), a0.y + a1.y + d2 * bf2f(su.y),
                           a0.z + a1.z + d2 * bf2f(su.z), a0.w + a1.w + d2 * bf2f(su.w));
    *(float4*)(agg + (long)node * F + q * 4) = o;
}

// out[N,FOUT] = relu(X[N,K] @ W[K,FOUT] + bias); thread = (2 nodes, 4 feats), W in LDS.
// BF16OUT: store ushort4 bf16. FUSE_POOL: hierarchical max-pool (2-graph LDS
// window, zero-skipping flush; direct global atomics if rel >= 2).
template<int K, int FOUT, bool FUSE_POOL, bool BF16OUT>
__global__ __launch_bounds__(256)
void gemm_kernel(const float* __restrict__ X, const float* __restrict__ W,
                 const float* __restrict__ bias, void* __restrict__ out,
                 const int* __restrict__ batch, unsigned int* __restrict__ g, int N) {
    constexpr int TPP = FOUT / 4;          // threads per node-pair
    constexpr int NPB = 2 * (256 / TPP);   // nodes per block
    __shared__ float ws[K * FOUT];
    __shared__ unsigned int gma[FUSE_POOL ? 2 * FOUT : 1];
    __shared__ int gfirst;
    for (int i = threadIdx.x; i < K * FOUT; i += 256) ws[i] = W[i];
    if (FUSE_POOL) {
        if (threadIdx.x == 0) gfirst = batch[min((int)(blockIdx.x * NPB), N - 1)];
        for (int i = threadIdx.x; i < 2 * FOUT; i += 256) gma[i] = 0u;
    }
    __syncthreads();

    int idx = blockIdx.x * 256 + threadIdx.x;
    int p = idx / TPP, q = idx % TPP;
    int n0 = p * 2;
    bool valid = n0 < N;
    bool has1 = (n0 + 1) < N;
    if (!FUSE_POOL && !valid) return;   // no later barriers on this path
    int cn0 = valid ? n0 : 0;
    int cn1 = has1 ? (n0 + 1) : cn0;
    const float4* xr0 = (const float4*)(X + (long)cn0 * K);
    const float4* xr1 = (const float4*)(X + (long)cn1 * K);
    const float* wq = ws + q * 4;
    float4 a0 = make_float4(0.f, 0.f, 0.f, 0.f);
    float4 a1 = make_float4(0.f, 0.f, 0.f, 0.f);
#pragma unroll 4
    for (int i = 0; i < K / 4; ++i) {
        float4 x0 = xr0[i];
        float4 x1 = xr1[i];
        const float* xx0 = (const float*)&x0;
        const float* xx1 = (const float*)&x1;
#pragma unroll
        for (int j = 0; j < 4; ++j) {
            float4 wv = *(const float4*)(wq + (i * 4 + j) * FOUT);
            float v0 = xx0[j], v1 = xx1[j];
            a0.x += v0 * wv.x; a0.y += v0 * wv.y; a0.z += v0 * wv.z; a0.w += v0 * wv.w;
            a1.x += v1 * wv.x; a1.y += v1 * wv.y; a1.z += v1 * wv.z; a1.w += v1 * wv.w;
        }
    }
    float4 bv = *(const float4*)(bias + q * 4);
    a0.x = fmaxf(a0.x + bv.x, 0.f); a0.y = fmaxf(a0.y + bv.y, 0.f);
    a0.z = fmaxf(a0.z + bv.z, 0.f); a0.w = fmaxf(a0.w + bv.w, 0.f);
    a1.x = fmaxf(a1.x + bv.x, 0.f); a1.y = fmaxf(a1.y + bv.y, 0.f);
    a1.z = fmaxf(a1.z + bv.z, 0.f); a1.w = fmaxf(a1.w + bv.w, 0.f);

    if (!FUSE_POOL) {
        if (BF16OUT) {
            ushort* ob = (ushort*)out;
            *(ushort4*)(ob + (long)n0 * FOUT + q * 4) =
                make_ushort4(f2bf(a0.x), f2bf(a0.y), f2bf(a0.z), f2bf(a0.w));
            if (has1)
                *(ushort4*)(ob + (long)(n0 + 1) * FOUT + q * 4) =
                    make_ushort4(f2bf(a1.x), f2bf(a1.y), f2bf(a1.z), f2bf(a1.w));
        } else {
            float* of = (float*)out;
            *(float4*)(of + (long)n0 * FOUT + q * 4) = a0;
            if (has1) *(float4*)(of + (long)(n0 + 1) * FOUT + q * 4) = a1;
        }
        return;
    }

    // ---- hierarchical pool ----
    auto push4 = [&](const float4& a, int node) {
        unsigned int bx = __float_as_uint(a.x), by = __float_as_uint(a.y);
        unsigned int bz = __float_as_uint(a.z), bw = __float_as_uint(a.w);
        int rel = batch[node] - gfirst;
        if (rel < 2) {
            unsigned int* d = gma + rel * FOUT + q * 4;
            atomicMax(d + 0, bx); atomicMax(d + 1, by);
            atomicMax(d + 2, bz); atomicMax(d + 3, bw);
        } else {
            unsigned int* d = g + (long)batch[node] * FOUT + q * 4;
            atomicMax(d + 0, bx); atomicMax(d + 1, by);
            atomicMax(d + 2, bz); atomicMax(d + 3, bw);
        }
    };
    if (valid) {
        push4(a0, n0);
        if (has1) push4(a1, n0 + 1);
    }
    __syncthreads();
    for (int i = threadIdx.x; i < 2 * FOUT; i += 256) {
        unsigned int v = gma[i];
        if (v) atomicMax(&g[(long)(gfirst + i / FOUT) * FOUT + (i % FOUT)], v);
    }
}

// one block per graph: relu(g@Wfc1+bfc1) @ Wfc2 + bfc2 -> softmax
__global__ void fc_kernel(const float* __restrict__ g, const float* __restrict__ Wfc1,
                          const float* __restrict__ bfc1, const float* __restrict__ Wfc2,
                          const float* __restrict__ bfc2, float* __restrict__ out) {
    __shared__ float gs[128];
    __shared__ float red0[256], red1[256];
    int b = blockIdx.x, tid = threadIdx.x;
    if (tid < 128) gs[tid] = g[b * 128 + tid];
    __syncthreads();
    float h0 = bfc1[tid], h1 = bfc1[tid + 256];
    for (int k = 0; k < 128; ++k) {
        float gv = gs[k];
        h0 += gv * Wfc1[k * 512 + tid];
        h1 += gv * Wfc1[k * 512 + tid + 256];
    }
    h0 = fmaxf(h0, 0.f); h1 = fmaxf(h1, 0.f);
    red0[tid] = h0 * Wfc2[tid * 2 + 0] + h1 * Wfc2[(tid + 256) * 2 + 0];
    red1[tid] = h0 * Wfc2[tid * 2 + 1] + h1 * Wfc2[(tid + 256) * 2 + 1];
    __syncthreads();
    for (int s = 128; s > 0; s >>= 1) {
        if (tid < s) { red0[tid] += red0[tid + s]; red1[tid] += red1[tid + s]; }
        __syncthreads();
    }
    if (tid == 0) {
        float L0 = red0[0] + bfc2[0], L1 = red1[0] + bfc2[1];
        float m = fmaxf(L0, L1);
        float e0 = expf(L0 - m), e1 = expf(L1 - m);
        float inv = 1.f / (e0 + e1);
        out[b * 2 + 0] = e0 * inv;
        out[b * 2 + 1] = e1 * inv;
    }
}

extern "C" void kernel_launch(void* const* d_in, const int* in_sizes, int n_in,
                              void* d_out, int out_size, void* d_ws, size_t ws_size,
                              hipStream_t stream) {
    const float* x     = (const float*)d_in[0];
    const int*   ei    = (const int*)d_in[1];
    const float* ew    = (const float*)d_in[2];
    const int*   batch = (const int*)d_in[3];
    const float* W1    = (const float*)d_in[4];
    const float* b1    = (const float*)d_in[5];
    const float* W2    = (const float*)d_in[6];
    const float* b2    = (const float*)d_in[7];
    const float* W3    = (const float*)d_in[8];
    const float* b3    = (const float*)d_in[9];
    const float* Wfc1  = (const float*)d_in[10];
    const float* bfc1  = (const float*)d_in[11];
    const float* Wfc2  = (const float*)d_in[12];
    const float* bfc2  = (const float*)d_in[13];

    const int N = in_sizes[3];      // 100000
    const int E = in_sizes[2];      // 1600000
    const int* row = ei;
    const int* col = ei + E;

    char* ws = (char*)d_ws;
    float* dinv   = (float*)ws;              ws += align256((size_t)N * 4);
    unsigned long long* packed = (unsigned long long*)ws; ws += align256((size_t)N * 8);
    int*   offs   = (int*)ws;                ws += align256((size_t)(N + 1) * 4);
    int*   bsums  = (int*)ws;                ws += align256((size_t)1024 * 4);
    int2*  perm   = (int2*)ws;               ws += align256((size_t)E * 8);
    float* bufA   = (float*)ws;              ws += align256((size_t)N * 128 * 4);  // agg f32
    ushort* bufH  = (ushort*)ws;             ws += align256((size_t)N * 128 * 2);  // H bf16
    ushort* xbf   = (ushort*)ws;             ws += align256((size_t)N * 40 * 2);   // x bf16
    float* g      = (float*)ws;              ws += align256((size_t)512 * 128 * 4);
    int*   rank   = (int*)bufA;   // rank[E] (6.4MB) aliases bufA — dead before gather1

    const int B = 256;
    const int nScanBlocks = cdiv(N, SCHUNK);   // 98 for N=100000 (<= 1024)

    // --- gcn_norm + CSR build ---
    hipMemsetAsync(packed, 0, (size_t)N * 8, stream);
    deg_count_kernel<<<cdiv(E, B), B, 0, stream>>>(col, ew, packed, rank, E);
    scanA_kernel<<<nScanBlocks, B, 0, stream>>>(packed, dinv, bsums, N);
    scanB_kernel<<<1, 1024, 0, stream>>>(bsums, offs, nScanBlocks, N);
    scanC_kernel<<<nScanBlocks, B, 0, stream>>>(packed, bsums, offs, N);
    fill_kernel<<<cdiv(E, B), B, 0, stream>>>(row, col, ew, rank, dinv, offs, perm, E);
    f2bf_kernel<<<cdiv((long)N * 10, B), B, 0, stream>>>(x, xbf, N * 10);

    const long npair_thr = ((long)(N + 1) / 2);

    // --- conv1: agg = A*x (40-wide bf16), H1 = relu(agg@W1 + b1) -> bufH (bf16) ---
    gather_kernel<40><<<cdiv((long)N * 10, B), B, 0, stream>>>(
        offs, perm, xbf, dinv, bufA, N);
    gemm_kernel<40, 40, false, true><<<cdiv(npair_thr * 10, B), B, 0, stream>>>(
        bufA, W1, b1, bufH, nullptr, nullptr, N);

    // --- conv2: agg = A*H1 (40-wide bf16), H2 = relu(agg@W2 + b2) -> bufH (bf16) ---
    gather_kernel<40><<<cdiv((long)N * 10, B), B, 0, stream>>>(
        offs, perm, bufH, dinv, bufA, N);
    gemm_kernel<40, 80, false, true><<<cdiv(npair_thr * 20, B), B, 0, stream>>>(
        bufA, W2, b2, bufH, nullptr, nullptr, N);

    // --- conv3: agg = A*H2 (80-wide bf16), pool(relu(agg@W3 + b3)) -> g ---
    gather_kernel<80><<<cdiv((long)N * 20, B), B, 0, stream>>>(
        offs, perm, bufH, dinv, bufA, N);
    hipMemsetAsync(g, 0, (size_t)512 * 128 * 4, stream);
    gemm_kernel<80, 128, true, false><<<cdiv(npair_thr * 32, B), B, 0, stream>>>(
        bufA, W3, b3, nullptr, batch, (unsigned int*)g, N);

    // --- MLP + softmax ---
    fc_kernel<<<512, 256, 0, stream>>>(g, Wfc1, bfc1, Wfc2, bfc2, (float*)d_out);
}